// Round 4
// baseline (1695.013 us; speedup 1.0000x reference)
//
#include <hip/hip_runtime.h>

#define NC   512      // BATCH(8) * 8 * 8
#define INC  32
#define HID  64
#define OUTC 32
#define STR  65       // padded LDS tile stride: bank=(lc+j)&31 -> 2-way max

__device__ __forceinline__ float gelu_f(float v){
    return 0.5f * v * (1.0f + erff(v * 0.70710678118654752f));
}

// ---------------- K1: fused MLP layer-1 + GELU + per-cluster pooling ----------------
// Weights are wave-uniform: read via uniform const loads (compiler -> s_load, SGPR
// operands to v_fmac), NOT LDS. LDS holds only the 64x64 cluster accumulator tile.
__global__ __launch_bounds__(256, 4) void k_src(
    const float* __restrict__ x, const float* __restrict__ sc,
    const float* __restrict__ Wv1, const float* __restrict__ bv1,
    float* __restrict__ partial, int* __restrict__ pcnt,
    int npb, int ppb, int bpb)
{
    __shared__ float acc[64*STR];
    __shared__ int   cntl[64];
    const int t = threadIdx.x;
    const int batch = blockIdx.x / bpb;
    const int pb    = blockIdx.x % bpb;

    for (int k = t; k < 64*STR; k += 256) acc[k] = 0.0f;
    if (t < 64) cntl[t] = 0;
    __syncthreads();

    const int base = batch * npb;
    const int s0 = pb * ppb;
    int s1 = s0 + ppb; if (s1 > npb) s1 = npb;

    for (int p = s0 + t; p < s1; p += 256){
        const int i = base + p;
        const float cx = sc[2*i], cy = sc[2*i+1];
        int ix = (int)(cx * 8.0f); ix = ix < 0 ? 0 : (ix > 7 ? 7 : ix);
        int iy = (int)(cy * 8.0f); iy = iy < 0 ? 0 : (iy > 7 ? 7 : iy);
        const int lc = (iy << 3) + ix;   // local cluster within batch

        float xv[INC];
        {
            const float4* xr = (const float4*)(x + (size_t)i * INC);
            #pragma unroll
            for (int q = 0; q < INC/4; q++){
                float4 v = xr[q];
                xv[4*q+0] = v.x; xv[4*q+1] = v.y; xv[4*q+2] = v.z; xv[4*q+3] = v.w;
            }
        }
        float h[HID];
        #pragma unroll
        for (int j = 0; j < HID; j++) h[j] = bv1[j];       // uniform -> s_load
        #pragma unroll
        for (int k = 0; k < INC; k++){                     // fully unrolled: const idx
            const float xk = xv[k];
            #pragma unroll
            for (int j = 0; j < HID; j++)
                h[j] += xk * Wv1[k*HID + j];               // uniform -> s_load
        }
        #pragma unroll
        for (int j = 0; j < HID; j++)
            unsafeAtomicAdd(&acc[lc*STR + j], gelu_f(h[j]));
        atomicAdd(&cntl[lc], 1);
    }
    __syncthreads();

    float* pt = partial + (size_t)blockIdx.x * 4096;
    for (int k = t; k < 4096; k += 256){
        const int r = k >> 6, cc = k & 63;
        pt[k] = acc[r*STR + cc];
    }
    if (t < 64) pcnt[blockIdx.x * 64 + t] = cntl[t];
}

// ---------------- K2: reduce partials, then mean -> @Wv2+bv2 -> @Wt1[2:]+bt1 -> z ----
__global__ void k_cluster(const float* __restrict__ partial, const int* __restrict__ pcnt,
                          const float* __restrict__ Wv2, const float* __restrict__ bv2,
                          const float* __restrict__ Wt1, const float* __restrict__ bt1,
                          float* __restrict__ z, int bpb)
{
    __shared__ float m[HID];
    __shared__ float ph[HID];
    const int c = blockIdx.x, j = threadIdx.x;  // 64 threads
    const int batch = c >> 6, lc = c & 63;

    float s = 0.0f;
    int n = 0;
    const size_t pb0 = (size_t)batch * bpb;
    for (int b = 0; b < bpb; b++){
        s += partial[(pb0 + b) * 4096 + (lc << 6) + j];
        n += pcnt[(pb0 + b) * 64 + lc];
    }
    const float inv = (n > 0) ? (1.0f / (float)n) : 0.0f;
    m[j] = s * inv;
    __syncthreads();
    float a = bv2[j];
    #pragma unroll 8
    for (int i = 0; i < HID; i++) a += m[i] * Wv2[i*HID + j];
    if (n == 0) a = 0.0f;   // reference: pooled = 0 for empty cluster
    ph[j] = a;
    __syncthreads();
    float b = bt1[j];
    #pragma unroll 8
    for (int i = 0; i < HID; i++) b += ph[i] * Wt1[(2 + i)*HID + j];
    z[c*HID + j] = b;
}

// ---------------- K3: per-target-point: gelu(z[cl] + cx*Wt1[0] + cy*Wt1[1]) @ Wt2 + bt2 ----
// All weights via uniform scalar loads; z[cl] rows from L1/L2 (128 KB table).
__global__ __launch_bounds__(256, 4) void k_tgt(
    const float* __restrict__ tc, const int* __restrict__ tb,
    const float* __restrict__ z, const float* __restrict__ Wt1,
    const float* __restrict__ Wt2, const float* __restrict__ bt2,
    float* __restrict__ out, int n)
{
    const int t = threadIdx.x;
    const int i = blockIdx.x * 256 + t;
    if (i >= n) return;
    const float cx = tc[2*i], cy = tc[2*i+1];
    int ix = (int)(cx * 8.0f); ix = ix < 0 ? 0 : (ix > 7 ? 7 : ix);
    int iy = (int)(cy * 8.0f); iy = iy < 0 ? 0 : (iy > 7 ? 7 : iy);
    const int cl = (tb[i] << 6) + (iy << 3) + ix;

    float g[HID];
    {
        const float4* zr = (const float4*)(z + cl*HID);
        #pragma unroll
        for (int q = 0; q < HID/4; q++){
            float4 v = zr[q];
            g[4*q+0] = v.x; g[4*q+1] = v.y; g[4*q+2] = v.z; g[4*q+3] = v.w;
        }
    }
    #pragma unroll
    for (int j = 0; j < HID; j++){
        float pre = g[j] + cx * Wt1[j] + cy * Wt1[HID + j];   // uniform -> s_load
        g[j] = gelu_f(pre);
    }
    float acc[OUTC];
    #pragma unroll
    for (int o = 0; o < OUTC; o++) acc[o] = bt2[o];           // uniform -> s_load
    #pragma unroll
    for (int j = 0; j < HID; j++){                            // fully unrolled
        const float gj = g[j];
        #pragma unroll
        for (int o = 0; o < OUTC; o++)
            acc[o] += gj * Wt2[j*OUTC + o];                   // uniform -> s_load
    }
    float4* orow = (float4*)(out + (size_t)i * OUTC);
    #pragma unroll
    for (int q = 0; q < OUTC/4; q++){
        orow[q] = make_float4(acc[4*q+0], acc[4*q+1], acc[4*q+2], acc[4*q+3]);
    }
}

extern "C" void kernel_launch(void* const* d_in, const int* in_sizes, int n_in,
                              void* d_out, int out_size, void* d_ws, size_t ws_size,
                              hipStream_t stream)
{
    const float* x   = (const float*)d_in[0];
    const float* sc  = (const float*)d_in[1];
    const int*   sb  = (const int*)  d_in[2];  (void)sb;
    const float* tc  = (const float*)d_in[3];
    const int*   tb  = (const int*)  d_in[4];
    const float* Wv1 = (const float*)d_in[5];
    const float* bv1 = (const float*)d_in[6];
    const float* Wv2 = (const float*)d_in[7];
    const float* bv2 = (const float*)d_in[8];
    const float* Wt1 = (const float*)d_in[9];
    const float* bt1 = (const float*)d_in[10];
    const float* Wt2 = (const float*)d_in[11];
    const float* bt2 = (const float*)d_in[12];
    float* out = (float*)d_out;

    const int n   = in_sizes[2];     // total points
    const int npb = n / 8;           // points per batch sample (src_batch = repeat)

    // blocks-per-batch sized by workspace: per-block partial = 4096 f32 + 64 int
    const size_t perB = 8ull * (4096 + 64) * 4;      // bytes per unit of BPB
    size_t avail = (ws_size > (1u << 20)) ? (ws_size - (1u << 20)) : 0;
    int bpb = (int)(avail / perB);
    if (bpb > 128) bpb = 128;
    if (bpb < 1)   bpb = 1;
    const int ppb = (npb + bpb - 1) / bpb;
    const int nblk = 8 * bpb;

    char* ws = (char*)d_ws;
    float* partial = (float*)(ws);                                    // nblk*4096*4
    int*   pcnt    = (int*)(ws + (size_t)nblk * 4096 * 4);            // nblk*64*4
    float* z       = (float*)(ws + (size_t)nblk * 4096 * 4 + (size_t)nblk * 64 * 4);

    k_src    <<<nblk, 256, 0, stream>>>(x, sc, Wv1, bv1, partial, pcnt, npb, ppb, bpb);
    k_cluster<<<NC, HID, 0, stream>>>(partial, pcnt, Wv2, bv2, Wt1, bt1, z, bpb);
    k_tgt    <<<(n + 255)/256, 256, 0, stream>>>(tc, tb, z, Wt1, Wt2, bt2, out, n);
}

// Round 5
// 371.667 us; speedup vs baseline: 4.5606x; 4.5606x over previous
//
#include <hip/hip_runtime.h>

#define NC   512      // BATCH(8) * 8 * 8
#define INC  32
#define HID  64
#define OUTC 32
#define STR  65       // padded LDS tile stride

typedef __attribute__((ext_vector_type(8))) __bf16 bf16x8;
typedef __attribute__((ext_vector_type(4))) float  f32x4;

static __device__ __forceinline__ f32x4 mfma16(bf16x8 a, bf16x8 b, f32x4 c){
    return __builtin_amdgcn_mfma_f32_16x16x32_bf16(a, b, c, 0, 0, 0);
}

__device__ __forceinline__ float gelu_f(float v){
    return 0.5f * v * (1.0f + erff(v * 0.70710678118654752f));
}

// split 8 f32 into hi/lo bf16 fragments (x ~= hi + lo, err <= 2^-16 |x|)
__device__ __forceinline__ void split8(const float* f, bf16x8& hi, bf16x8& lo){
    union { unsigned short us[8]; bf16x8 v; } H, L;
    #pragma unroll
    for (int j = 0; j < 8; j++){
        float xf = f[j];
        unsigned int ux = __float_as_uint(xf);
        float hf = __uint_as_float(ux & 0xFFFF0000u);
        float lf = xf - hf;                      // exact in f32
        H.us[j] = (unsigned short)(ux >> 16);
        L.us[j] = (unsigned short)(__float_as_uint(lf) >> 16);
    }
    hi = H.v; lo = L.v;
}

// ---------------- K1: MFMA MLP layer-1 + GELU + per-cluster pooling ----------------
// Block = bpb-th slice of one batch (T 16-point tiles). Wave w handles tiles w, w+4,...
// B-fragments (Wv1 hi/lo) live in VGPRs for the whole kernel; A streamed from x.
__global__ __launch_bounds__(256, 4) void k_src(
    const float* __restrict__ x, const float* __restrict__ sc,
    const float* __restrict__ Wv1, const float* __restrict__ bv1,
    float* __restrict__ partial, int* __restrict__ pcnt,
    int npb, int T, int bpb)
{
    __shared__ float accL[64*STR];
    __shared__ int   cntl[64];
    const int t = threadIdx.x;
    const int wave = t >> 6, lane = t & 63;
    const int lrow = lane & 15, lgrp = lane >> 4;
    const int batch = blockIdx.x / bpb;
    const int pb    = blockIdx.x % bpb;

    for (int k = t; k < 64*STR; k += 256) accL[k] = 0.0f;
    if (t < 64) cntl[t] = 0;

    // preload B-fragments: lane holds Wv1[8*lgrp+j][16*nt+lrow]
    bf16x8 Bh[4], Bl[4];
    float bnt[4];
    #pragma unroll
    for (int nt = 0; nt < 4; nt++){
        float w[8];
        #pragma unroll
        for (int j = 0; j < 8; j++) w[j] = Wv1[(8*lgrp + j)*HID + 16*nt + lrow];
        split8(w, Bh[nt], Bl[nt]);
        bnt[nt] = bv1[16*nt + lrow];
    }
    __syncthreads();

    const int blk_base = batch * npb + pb * T * 16;

    for (int tt = wave; tt < T; tt += 4){
        const int ptb = blk_base + tt * 16;
        // cluster id of "my" A-row point (replicated across the 4 lane-groups)
        const float2 s2 = ((const float2*)sc)[ptb + lrow];
        int ix = (int)(s2.x * 8.0f); ix = ix < 0 ? 0 : (ix > 7 ? 7 : ix);
        int iy = (int)(s2.y * 8.0f); iy = iy < 0 ? 0 : (iy > 7 ? 7 : iy);
        const int lc = (iy << 3) + ix;

        // A fragment: x[ptb+lrow][8*lgrp + j]
        float xa[8];
        {
            const float4* xr = (const float4*)(x + (size_t)(ptb + lrow)*INC + 8*lgrp);
            float4 a0 = xr[0], a1 = xr[1];
            xa[0]=a0.x; xa[1]=a0.y; xa[2]=a0.z; xa[3]=a0.w;
            xa[4]=a1.x; xa[5]=a1.y; xa[6]=a1.z; xa[7]=a1.w;
        }
        bf16x8 Ah, Al;
        split8(xa, Ah, Al);

        f32x4 acc[4];
        #pragma unroll
        for (int nt = 0; nt < 4; nt++) acc[nt] = (f32x4){0.f,0.f,0.f,0.f};
        #pragma unroll
        for (int nt = 0; nt < 4; nt++) acc[nt] = mfma16(Al, Bh[nt], acc[nt]);
        #pragma unroll
        for (int nt = 0; nt < 4; nt++) acc[nt] = mfma16(Ah, Bl[nt], acc[nt]);
        #pragma unroll
        for (int nt = 0; nt < 4; nt++) acc[nt] = mfma16(Ah, Bh[nt], acc[nt]);

        if (lane < 16) atomicAdd(&cntl[lc], 1);

        #pragma unroll
        for (int nt = 0; nt < 4; nt++){
            #pragma unroll
            for (int q = 0; q < 4; q++){
                const int row = 4*lgrp + q;                 // D row = point-in-tile
                const int lcq = __shfl(lc, row, 64);
                const float val = gelu_f(acc[nt][q] + bnt[nt]);
                unsafeAtomicAdd(&accL[lcq*STR + 16*nt + lrow], val);
            }
        }
    }
    __syncthreads();

    float* pt = partial + (size_t)blockIdx.x * 4096;
    for (int k = t; k < 4096; k += 256){
        const int r = k >> 6, cc = k & 63;
        pt[k] = accL[r*STR + cc];
    }
    if (t < 64) pcnt[blockIdx.x * 64 + t] = cntl[t];
}

// ---------------- K2: reduce partials, then mean -> @Wv2+bv2 -> @Wt1[2:]+bt1 -> z ----
__global__ void k_cluster(const float* __restrict__ partial, const int* __restrict__ pcnt,
                          const float* __restrict__ Wv2, const float* __restrict__ bv2,
                          const float* __restrict__ Wt1, const float* __restrict__ bt1,
                          float* __restrict__ z, int bpb)
{
    __shared__ float m[HID];
    __shared__ float ph[HID];
    const int c = blockIdx.x, j = threadIdx.x;  // 64 threads
    const int batch = c >> 6, lc = c & 63;

    float s = 0.0f;
    int n = 0;
    const size_t pb0 = (size_t)batch * bpb;
    for (int b = 0; b < bpb; b++){
        s += partial[(pb0 + b) * 4096 + (lc << 6) + j];
        n += pcnt[(pb0 + b) * 64 + lc];
    }
    const float inv = (n > 0) ? (1.0f / (float)n) : 0.0f;
    m[j] = s * inv;
    __syncthreads();
    float a = bv2[j];
    #pragma unroll 8
    for (int i = 0; i < HID; i++) a += m[i] * Wv2[i*HID + j];
    if (n == 0) a = 0.0f;   // reference: pooled = 0 for empty cluster
    ph[j] = a;
    __syncthreads();
    float b = bt1[j];
    #pragma unroll 8
    for (int i = 0; i < HID; i++) b += ph[i] * Wt1[(2 + i)*HID + j];
    z[c*HID + j] = b;
}

// ---------------- K3: MFMA target MLP: out = gelu(z[cl]+cx*W0+cy*W1) @ Wt2 + bt2 ----
__global__ __launch_bounds__(256, 3) void k_tgt(
    const float* __restrict__ tc, const int* __restrict__ tb,
    const float* __restrict__ z, const float* __restrict__ Wt1,
    const float* __restrict__ Wt2, const float* __restrict__ bt2,
    float* __restrict__ out, int n, int ntile, int TT)
{
    const int t = threadIdx.x;
    const int wave = t >> 6, lane = t & 63;
    const int lrow = lane & 15, lgrp = lane >> 4;

    // preload B-fragments of Wt2 and the coord-row slices of Wt1
    bf16x8 Bh[2][2], Bl[2][2];
    float w0v[2][8], w1v[2][8], bo[2];
    #pragma unroll
    for (int kt = 0; kt < 2; kt++){
        #pragma unroll
        for (int nt = 0; nt < 2; nt++){
            float w[8];
            #pragma unroll
            for (int j = 0; j < 8; j++)
                w[j] = Wt2[(32*kt + 8*lgrp + j)*OUTC + 16*nt + lrow];
            split8(w, Bh[kt][nt], Bl[kt][nt]);
        }
        #pragma unroll
        for (int j = 0; j < 8; j++){
            const int ch = 32*kt + 8*lgrp + j;
            w0v[kt][j] = Wt1[ch];
            w1v[kt][j] = Wt1[HID + ch];
        }
    }
    bo[0] = bt2[lrow]; bo[1] = bt2[16 + lrow];

    for (int tt = wave; tt < TT; tt += 4){
        const int g = blockIdx.x * TT + tt;
        if (g >= ntile) break;
        const int ptb = g * 16;
        int pt = ptb + lrow; if (pt >= n) pt = n - 1;     // clamp (tail-safe)
        const float2 c2 = ((const float2*)tc)[pt];
        int ix = (int)(c2.x * 8.0f); ix = ix < 0 ? 0 : (ix > 7 ? 7 : ix);
        int iy = (int)(c2.y * 8.0f); iy = iy < 0 ? 0 : (iy > 7 ? 7 : iy);
        const int cl = (tb[pt] << 6) + (iy << 3) + ix;

        bf16x8 Ah[2], Al[2];
        #pragma unroll
        for (int kt = 0; kt < 2; kt++){
            float gv[8];
            const float4* zr = (const float4*)(z + (size_t)cl*HID + 32*kt + 8*lgrp);
            float4 z0 = zr[0], z1 = zr[1];
            float zv[8] = {z0.x,z0.y,z0.z,z0.w,z1.x,z1.y,z1.z,z1.w};
            #pragma unroll
            for (int j = 0; j < 8; j++)
                gv[j] = gelu_f(zv[j] + c2.x * w0v[kt][j] + c2.y * w1v[kt][j]);
            split8(gv, Ah[kt], Al[kt]);
        }

        f32x4 acc[2];
        #pragma unroll
        for (int nt = 0; nt < 2; nt++) acc[nt] = (f32x4){0.f,0.f,0.f,0.f};
        #pragma unroll
        for (int nt = 0; nt < 2; nt++){
            #pragma unroll
            for (int kt = 0; kt < 2; kt++){
                acc[nt] = mfma16(Al[kt], Bh[kt][nt], acc[nt]);
                acc[nt] = mfma16(Ah[kt], Bl[kt][nt], acc[nt]);
                acc[nt] = mfma16(Ah[kt], Bh[kt][nt], acc[nt]);
            }
        }

        #pragma unroll
        for (int nt = 0; nt < 2; nt++){
            #pragma unroll
            for (int q = 0; q < 4; q++){
                const int row = 4*lgrp + q;
                const int ptq = ptb + row;
                if (ptq < n)
                    out[(size_t)ptq*OUTC + 16*nt + lrow] = acc[nt][q] + bo[nt];
            }
        }
    }
}

extern "C" void kernel_launch(void* const* d_in, const int* in_sizes, int n_in,
                              void* d_out, int out_size, void* d_ws, size_t ws_size,
                              hipStream_t stream)
{
    const float* x   = (const float*)d_in[0];
    const float* sc  = (const float*)d_in[1];
    const int*   sb  = (const int*)  d_in[2];  (void)sb;
    const float* tc  = (const float*)d_in[3];
    const int*   tb  = (const int*)  d_in[4];
    const float* Wv1 = (const float*)d_in[5];
    const float* bv1 = (const float*)d_in[6];
    const float* Wv2 = (const float*)d_in[7];
    const float* bv2 = (const float*)d_in[8];
    const float* Wt1 = (const float*)d_in[9];
    const float* bt1 = (const float*)d_in[10];
    const float* Wt2 = (const float*)d_in[11];
    const float* bt2 = (const float*)d_in[12];
    float* out = (float*)d_out;

    const int n   = in_sizes[2];     // total points
    const int npb = n / 8;           // points per batch (src_batch = repeat)
    const int tiles_pb = npb / 16;   // 6250 for 100k

    // pick bpb = largest divisor of tiles_pb <= 128 whose partials fit in ws
    int bpb = 1;
    for (int d = 128; d >= 1; d--){
        if (tiles_pb % d) continue;
        size_t need = (size_t)(8*d) * (4096 + 64) * 4 + (size_t)NC * HID * 4 + 4096;
        if (need <= ws_size){ bpb = d; break; }
    }
    const int T    = tiles_pb / bpb;
    const int nblk = 8 * bpb;

    char* ws = (char*)d_ws;
    float* partial = (float*)(ws);                                    // nblk*4096*4
    int*   pcnt    = (int*)(ws + (size_t)nblk * 4096 * 4);            // nblk*64*4
    float* z       = (float*)(ws + (size_t)nblk * 4096 * 4 + (size_t)nblk * 64 * 4);

    k_src    <<<nblk, 256, 0, stream>>>(x, sc, Wv1, bv1, partial, pcnt, npb, T, bpb);
    k_cluster<<<NC, HID, 0, stream>>>(partial, pcnt, Wv2, bv2, Wt1, bt1, z, bpb);

    const int ntile = (n + 15) / 16;
    const int TT = 80;
    const int nblk_t = (ntile + TT - 1) / TT;
    k_tgt    <<<nblk_t, 256, 0, stream>>>(tc, tb, z, Wt1, Wt2, bt2, out, n, ntile, TT);
}

// Round 6
// 357.997 us; speedup vs baseline: 4.7347x; 1.0382x over previous
//
#include <hip/hip_runtime.h>

#define NC   512      // BATCH(8) * 8 * 8
#define INC  32
#define HID  64
#define OUTC 32
#define STR  65       // padded LDS tile stride

typedef __attribute__((ext_vector_type(8))) __bf16 bf16x8;
typedef __attribute__((ext_vector_type(4))) float  f32x4;
typedef __attribute__((ext_vector_type(8))) float  f32x8;
typedef __attribute__((ext_vector_type(8))) unsigned int   u32x8;
typedef __attribute__((ext_vector_type(8))) unsigned short u16x8;

static __device__ __forceinline__ f32x4 mfma16(bf16x8 a, bf16x8 b, f32x4 c){
    return __builtin_amdgcn_mfma_f32_16x16x32_bf16(a, b, c, 0, 0, 0);
}

__device__ __forceinline__ float gelu_f(float v){
    return 0.5f * v * (1.0f + erff(v * 0.70710678118654752f));
}

// value-typed 3-term split: x ~= hi + lo (each bf16-truncated), no unions/pointers
__device__ __forceinline__ void split8v(f32x8 x, bf16x8& hi, bf16x8& lo){
    u32x8 ux = __builtin_bit_cast(u32x8, x);
    f32x8 hf = __builtin_bit_cast(f32x8, ux & 0xFFFF0000u);
    f32x8 lf = x - hf;                               // exact in f32
    u32x8 ul = __builtin_bit_cast(u32x8, lf);
    hi = __builtin_bit_cast(bf16x8, __builtin_convertvector(ux >> 16, u16x8));
    lo = __builtin_bit_cast(bf16x8, __builtin_convertvector(ul >> 16, u16x8));
}

// ---------------- K1: MFMA MLP layer-1 + GELU + per-cluster pooling ----------------
__global__ __launch_bounds__(256, 3) void k_src(
    const float* __restrict__ x, const float* __restrict__ sc,
    const float* __restrict__ Wv1, const float* __restrict__ bv1,
    float* __restrict__ partial, int* __restrict__ pcnt,
    int npb, int T, int bpb)
{
    __shared__ float accL[64*STR];
    __shared__ int   cntl[64];
    const int t = threadIdx.x;
    const int wave = t >> 6, lane = t & 63;
    const int lrow = lane & 15, lgrp = lane >> 4;
    const int batch = blockIdx.x / bpb;
    const int pb    = blockIdx.x % bpb;

    for (int k = t; k < 64*STR; k += 256) accL[k] = 0.0f;
    if (t < 64) cntl[t] = 0;

    // preload B-fragments: lane holds Wv1[8*lgrp+j][16*nt+lrow]
    bf16x8 Bh0, Bh1, Bh2, Bh3, Bl0, Bl1, Bl2, Bl3;
    float bnt0, bnt1, bnt2, bnt3;
    {
        f32x8 w;
        #pragma unroll
        for (int j = 0; j < 8; j++) w[j] = Wv1[(8*lgrp + j)*HID + 0*16 + lrow];
        split8v(w, Bh0, Bl0);  bnt0 = bv1[ 0 + lrow];
        #pragma unroll
        for (int j = 0; j < 8; j++) w[j] = Wv1[(8*lgrp + j)*HID + 1*16 + lrow];
        split8v(w, Bh1, Bl1);  bnt1 = bv1[16 + lrow];
        #pragma unroll
        for (int j = 0; j < 8; j++) w[j] = Wv1[(8*lgrp + j)*HID + 2*16 + lrow];
        split8v(w, Bh2, Bl2);  bnt2 = bv1[32 + lrow];
        #pragma unroll
        for (int j = 0; j < 8; j++) w[j] = Wv1[(8*lgrp + j)*HID + 3*16 + lrow];
        split8v(w, Bh3, Bl3);  bnt3 = bv1[48 + lrow];
    }
    __syncthreads();

    const int blk_base = batch * npb + pb * T * 16;

    for (int tt = wave; tt < T; tt += 4){
        const int ptb = blk_base + tt * 16;
        const float2 s2 = ((const float2*)sc)[ptb + lrow];
        int ix = (int)(s2.x * 8.0f); ix = ix < 0 ? 0 : (ix > 7 ? 7 : ix);
        int iy = (int)(s2.y * 8.0f); iy = iy < 0 ? 0 : (iy > 7 ? 7 : iy);
        const int lc = (iy << 3) + ix;

        // A fragment: x[ptb+lrow][8*lgrp + j]
        f32x8 xa = *(const f32x8*)(x + (size_t)(ptb + lrow)*INC + 8*lgrp);
        bf16x8 Ah, Al;
        split8v(xa, Ah, Al);

        f32x4 a0 = (f32x4){0.f,0.f,0.f,0.f}, a1 = a0, a2 = a0, a3 = a0;
        a0 = mfma16(Al, Bh0, a0); a1 = mfma16(Al, Bh1, a1);
        a2 = mfma16(Al, Bh2, a2); a3 = mfma16(Al, Bh3, a3);
        a0 = mfma16(Ah, Bl0, a0); a1 = mfma16(Ah, Bl1, a1);
        a2 = mfma16(Ah, Bl2, a2); a3 = mfma16(Ah, Bl3, a3);
        a0 = mfma16(Ah, Bh0, a0); a1 = mfma16(Ah, Bh1, a1);
        a2 = mfma16(Ah, Bh2, a2); a3 = mfma16(Ah, Bh3, a3);

        if (lane < 16) atomicAdd(&cntl[lc], 1);

        // 4 cluster ids for this lane's 4 D-rows (rows 4*lgrp+q)
        const int lcq0 = __shfl(lc, 4*lgrp + 0, 64);
        const int lcq1 = __shfl(lc, 4*lgrp + 1, 64);
        const int lcq2 = __shfl(lc, 4*lgrp + 2, 64);
        const int lcq3 = __shfl(lc, 4*lgrp + 3, 64);

        unsafeAtomicAdd(&accL[lcq0*STR +  0 + lrow], gelu_f(a0[0] + bnt0));
        unsafeAtomicAdd(&accL[lcq1*STR +  0 + lrow], gelu_f(a0[1] + bnt0));
        unsafeAtomicAdd(&accL[lcq2*STR +  0 + lrow], gelu_f(a0[2] + bnt0));
        unsafeAtomicAdd(&accL[lcq3*STR +  0 + lrow], gelu_f(a0[3] + bnt0));
        unsafeAtomicAdd(&accL[lcq0*STR + 16 + lrow], gelu_f(a1[0] + bnt1));
        unsafeAtomicAdd(&accL[lcq1*STR + 16 + lrow], gelu_f(a1[1] + bnt1));
        unsafeAtomicAdd(&accL[lcq2*STR + 16 + lrow], gelu_f(a1[2] + bnt1));
        unsafeAtomicAdd(&accL[lcq3*STR + 16 + lrow], gelu_f(a1[3] + bnt1));
        unsafeAtomicAdd(&accL[lcq0*STR + 32 + lrow], gelu_f(a2[0] + bnt2));
        unsafeAtomicAdd(&accL[lcq1*STR + 32 + lrow], gelu_f(a2[1] + bnt2));
        unsafeAtomicAdd(&accL[lcq2*STR + 32 + lrow], gelu_f(a2[2] + bnt2));
        unsafeAtomicAdd(&accL[lcq3*STR + 32 + lrow], gelu_f(a2[3] + bnt2));
        unsafeAtomicAdd(&accL[lcq0*STR + 48 + lrow], gelu_f(a3[0] + bnt3));
        unsafeAtomicAdd(&accL[lcq1*STR + 48 + lrow], gelu_f(a3[1] + bnt3));
        unsafeAtomicAdd(&accL[lcq2*STR + 48 + lrow], gelu_f(a3[2] + bnt3));
        unsafeAtomicAdd(&accL[lcq3*STR + 48 + lrow], gelu_f(a3[3] + bnt3));
    }
    __syncthreads();

    float* pt = partial + (size_t)blockIdx.x * 4096;
    for (int k = t; k < 4096; k += 256){
        const int r = k >> 6, cc = k & 63;
        pt[k] = accL[r*STR + cc];
    }
    if (t < 64) pcnt[blockIdx.x * 64 + t] = cntl[t];
}

// ---------------- K2: reduce partials, then mean -> @Wv2+bv2 -> @Wt1[2:]+bt1 -> z ----
__global__ void k_cluster(const float* __restrict__ partial, const int* __restrict__ pcnt,
                          const float* __restrict__ Wv2, const float* __restrict__ bv2,
                          const float* __restrict__ Wt1, const float* __restrict__ bt1,
                          float* __restrict__ z, int bpb)
{
    __shared__ float m[HID];
    __shared__ float ph[HID];
    const int c = blockIdx.x, j = threadIdx.x;  // 64 threads
    const int batch = c >> 6, lc = c & 63;

    float s = 0.0f;
    int n = 0;
    const size_t pb0 = (size_t)batch * bpb;
    for (int b = 0; b < bpb; b++){
        s += partial[(pb0 + b) * 4096 + (lc << 6) + j];
        n += pcnt[(pb0 + b) * 64 + lc];
    }
    const float inv = (n > 0) ? (1.0f / (float)n) : 0.0f;
    m[j] = s * inv;
    __syncthreads();
    float a = bv2[j];
    #pragma unroll 8
    for (int i = 0; i < HID; i++) a += m[i] * Wv2[i*HID + j];
    if (n == 0) a = 0.0f;   // reference: pooled = 0 for empty cluster
    ph[j] = a;
    __syncthreads();
    float b = bt1[j];
    #pragma unroll 8
    for (int i = 0; i < HID; i++) b += ph[i] * Wt1[(2 + i)*HID + j];
    z[c*HID + j] = b;
}

// ---------------- K3: MFMA target MLP: out = gelu(z[cl]+cx*W0+cy*W1) @ Wt2 + bt2 ----
__global__ __launch_bounds__(256, 3) void k_tgt(
    const float* __restrict__ tc, const int* __restrict__ tb,
    const float* __restrict__ z, const float* __restrict__ Wt1,
    const float* __restrict__ Wt2, const float* __restrict__ bt2,
    float* __restrict__ out, int n, int ntile, int TT)
{
    const int t = threadIdx.x;
    const int wave = t >> 6, lane = t & 63;
    const int lrow = lane & 15, lgrp = lane >> 4;

    // B-fragments of Wt2 (kt = K-tile, nt = N-tile), Wt1 coord rows, bias
    bf16x8 Bh00, Bh01, Bh10, Bh11, Bl00, Bl01, Bl10, Bl11;
    f32x8 w0v0, w0v1, w1v0, w1v1;
    {
        f32x8 w;
        #pragma unroll
        for (int j = 0; j < 8; j++) w[j] = Wt2[( 0 + 8*lgrp + j)*OUTC +  0 + lrow];
        split8v(w, Bh00, Bl00);
        #pragma unroll
        for (int j = 0; j < 8; j++) w[j] = Wt2[( 0 + 8*lgrp + j)*OUTC + 16 + lrow];
        split8v(w, Bh01, Bl01);
        #pragma unroll
        for (int j = 0; j < 8; j++) w[j] = Wt2[(32 + 8*lgrp + j)*OUTC +  0 + lrow];
        split8v(w, Bh10, Bl10);
        #pragma unroll
        for (int j = 0; j < 8; j++) w[j] = Wt2[(32 + 8*lgrp + j)*OUTC + 16 + lrow];
        split8v(w, Bh11, Bl11);
        #pragma unroll
        for (int j = 0; j < 8; j++){
            w0v0[j] = Wt1[ 0 + 8*lgrp + j];
            w0v1[j] = Wt1[32 + 8*lgrp + j];
            w1v0[j] = Wt1[HID +  0 + 8*lgrp + j];
            w1v1[j] = Wt1[HID + 32 + 8*lgrp + j];
        }
    }
    const float bo0 = bt2[lrow], bo1 = bt2[16 + lrow];

    for (int tt = wave; tt < TT; tt += 4){
        const int g = blockIdx.x * TT + tt;
        if (g >= ntile) break;
        const int ptb = g * 16;
        int pt = ptb + lrow; if (pt >= n) pt = n - 1;     // clamp (tail-safe)
        const float2 c2 = ((const float2*)tc)[pt];
        int ix = (int)(c2.x * 8.0f); ix = ix < 0 ? 0 : (ix > 7 ? 7 : ix);
        int iy = (int)(c2.y * 8.0f); iy = iy < 0 ? 0 : (iy > 7 ? 7 : iy);
        const int cl = (tb[pt] << 6) + (iy << 3) + ix;

        f32x8 z0 = *(const f32x8*)(z + (size_t)cl*HID +  0 + 8*lgrp);
        f32x8 z1 = *(const f32x8*)(z + (size_t)cl*HID + 32 + 8*lgrp);
        f32x8 g0, g1;
        #pragma unroll
        for (int j = 0; j < 8; j++){
            g0[j] = gelu_f(z0[j] + c2.x * w0v0[j] + c2.y * w1v0[j]);
            g1[j] = gelu_f(z1[j] + c2.x * w0v1[j] + c2.y * w1v1[j]);
        }
        bf16x8 Ah0, Al0, Ah1, Al1;
        split8v(g0, Ah0, Al0);
        split8v(g1, Ah1, Al1);

        f32x4 a0 = (f32x4){0.f,0.f,0.f,0.f}, a1 = a0;
        a0 = mfma16(Al0, Bh00, a0); a1 = mfma16(Al0, Bh01, a1);
        a0 = mfma16(Ah0, Bl00, a0); a1 = mfma16(Ah0, Bl01, a1);
        a0 = mfma16(Ah0, Bh00, a0); a1 = mfma16(Ah0, Bh01, a1);
        a0 = mfma16(Al1, Bh10, a0); a1 = mfma16(Al1, Bh11, a1);
        a0 = mfma16(Ah1, Bl10, a0); a1 = mfma16(Ah1, Bl11, a1);
        a0 = mfma16(Ah1, Bh10, a0); a1 = mfma16(Ah1, Bh11, a1);

        #pragma unroll
        for (int q = 0; q < 4; q++){
            const int ptq = ptb + 4*lgrp + q;
            if (ptq < n){
                out[(size_t)ptq*OUTC +  0 + lrow] = a0[q] + bo0;
                out[(size_t)ptq*OUTC + 16 + lrow] = a1[q] + bo1;
            }
        }
    }
}

extern "C" void kernel_launch(void* const* d_in, const int* in_sizes, int n_in,
                              void* d_out, int out_size, void* d_ws, size_t ws_size,
                              hipStream_t stream)
{
    const float* x   = (const float*)d_in[0];
    const float* sc  = (const float*)d_in[1];
    const int*   sb  = (const int*)  d_in[2];  (void)sb;
    const float* tc  = (const float*)d_in[3];
    const int*   tb  = (const int*)  d_in[4];
    const float* Wv1 = (const float*)d_in[5];
    const float* bv1 = (const float*)d_in[6];
    const float* Wv2 = (const float*)d_in[7];
    const float* bv2 = (const float*)d_in[8];
    const float* Wt1 = (const float*)d_in[9];
    const float* bt1 = (const float*)d_in[10];
    const float* Wt2 = (const float*)d_in[11];
    const float* bt2 = (const float*)d_in[12];
    float* out = (float*)d_out;

    const int n   = in_sizes[2];     // total points
    const int npb = n / 8;           // points per batch (src_batch = repeat)
    const int tiles_pb = npb / 16;   // 6250 for 100k

    // pick bpb = largest divisor of tiles_pb <= 128 whose partials fit in ws
    int bpb = 1;
    for (int d = 128; d >= 1; d--){
        if (tiles_pb % d) continue;
        size_t need = (size_t)(8*d) * (4096 + 64) * 4 + (size_t)NC * HID * 4 + 4096;
        if (need <= ws_size){ bpb = d; break; }
    }
    const int T    = tiles_pb / bpb;
    const int nblk = 8 * bpb;

    char* ws = (char*)d_ws;
    float* partial = (float*)(ws);                                    // nblk*4096*4
    int*   pcnt    = (int*)(ws + (size_t)nblk * 4096 * 4);            // nblk*64*4
    float* z       = (float*)(ws + (size_t)nblk * 4096 * 4 + (size_t)nblk * 64 * 4);

    k_src    <<<nblk, 256, 0, stream>>>(x, sc, Wv1, bv1, partial, pcnt, npb, T, bpb);
    k_cluster<<<NC, HID, 0, stream>>>(partial, pcnt, Wv2, bv2, Wt1, bt1, z, bpb);

    const int ntile = (n + 15) / 16;
    const int TT = 40;
    const int nblk_t = (ntile + TT - 1) / TT;
    k_tgt    <<<nblk_t, 256, 0, stream>>>(tc, tb, z, Wt1, Wt2, bt2, out, n, ntile, TT);
}

// Round 7
// 324.373 us; speedup vs baseline: 5.2255x; 1.1037x over previous
//
#include <hip/hip_runtime.h>

#define NC   512      // BATCH(8) * 8 * 8
#define INC  32
#define HID  64
#define OUTC 32
#define STR  65       // padded LDS stride for cluster accumulator
#define STRZ 68       // padded LDS stride for z slice (16B-aligned rows, bank-spread)

typedef __attribute__((ext_vector_type(8))) __bf16 bf16x8;
typedef __attribute__((ext_vector_type(4))) float  f32x4;
typedef __attribute__((ext_vector_type(8))) float  f32x8;
typedef __attribute__((ext_vector_type(8))) unsigned int   u32x8;
typedef __attribute__((ext_vector_type(8))) unsigned short u16x8;

static __device__ __forceinline__ f32x4 mfma16(bf16x8 a, bf16x8 b, f32x4 c){
    return __builtin_amdgcn_mfma_f32_16x16x32_bf16(a, b, c, 0, 0, 0);
}

// fast exact-GELU: erf via Abramowitz-Stegun 7.1.26 (|err|<=1.5e-7), v_exp_f32 + rcp
__device__ __forceinline__ float gelu_f(float v){
    const float s  = v * 0.70710678118654752f;
    const float as = fabsf(s);
    const float t  = __builtin_amdgcn_rcpf(__builtin_fmaf(0.3275911f, as, 1.0f));
    const float e  = __expf(-as * as);
    float p = __builtin_fmaf(1.061405429f, t, -1.453152027f);
    p = __builtin_fmaf(p, t, 1.421413741f);
    p = __builtin_fmaf(p, t, -0.284496736f);
    p = __builtin_fmaf(p, t, 0.254829592f);
    p = p * t;
    float er = __builtin_fmaf(-p, e, 1.0f);   // erf(|s|)
    er = copysignf(er, s);
    return 0.5f * v * (1.0f + er);
}

// value-typed 3-term split: x ~= hi + lo (each bf16-truncated)
__device__ __forceinline__ void split8v(f32x8 x, bf16x8& hi, bf16x8& lo){
    u32x8 ux = __builtin_bit_cast(u32x8, x);
    f32x8 hf = __builtin_bit_cast(f32x8, ux & 0xFFFF0000u);
    f32x8 lf = x - hf;                               // exact in f32
    u32x8 ul = __builtin_bit_cast(u32x8, lf);
    hi = __builtin_bit_cast(bf16x8, __builtin_convertvector(ux >> 16, u16x8));
    lo = __builtin_bit_cast(bf16x8, __builtin_convertvector(ul >> 16, u16x8));
}

// ---------------- K1: MFMA MLP layer-1 + GELU + per-cluster pooling ----------------
__global__ __launch_bounds__(256, 3) void k_src(
    const float* __restrict__ x, const float* __restrict__ sc,
    const float* __restrict__ Wv1, const float* __restrict__ bv1,
    float* __restrict__ partial, int* __restrict__ pcnt,
    int npb, int T, int bpb)
{
    __shared__ float accL[64*STR];
    __shared__ int   cntl[64];
    const int t = threadIdx.x;
    const int wave = t >> 6, lane = t & 63;
    const int lrow = lane & 15, lgrp = lane >> 4;
    const int batch = blockIdx.x / bpb;
    const int pb    = blockIdx.x % bpb;

    for (int k = t; k < 64*STR; k += 256) accL[k] = 0.0f;
    if (t < 64) cntl[t] = 0;

    // preload B-fragments: lane holds Wv1[8*lgrp+j][16*nt+lrow]
    bf16x8 Bh0, Bh1, Bh2, Bh3, Bl0, Bl1, Bl2, Bl3;
    float bnt0, bnt1, bnt2, bnt3;
    {
        f32x8 w;
        #pragma unroll
        for (int j = 0; j < 8; j++) w[j] = Wv1[(8*lgrp + j)*HID +  0 + lrow];
        split8v(w, Bh0, Bl0);  bnt0 = bv1[ 0 + lrow];
        #pragma unroll
        for (int j = 0; j < 8; j++) w[j] = Wv1[(8*lgrp + j)*HID + 16 + lrow];
        split8v(w, Bh1, Bl1);  bnt1 = bv1[16 + lrow];
        #pragma unroll
        for (int j = 0; j < 8; j++) w[j] = Wv1[(8*lgrp + j)*HID + 32 + lrow];
        split8v(w, Bh2, Bl2);  bnt2 = bv1[32 + lrow];
        #pragma unroll
        for (int j = 0; j < 8; j++) w[j] = Wv1[(8*lgrp + j)*HID + 48 + lrow];
        split8v(w, Bh3, Bl3);  bnt3 = bv1[48 + lrow];
    }
    __syncthreads();

    const int blk_base = batch * npb + pb * T * 16;

    // software pipeline: prefetch next tile's coords + x row into registers
    float2 s2_c; f32x8 xa_c;
    {
        const int ptb = blk_base + wave * 16;
        s2_c = ((const float2*)sc)[ptb + lrow];
        xa_c = *(const f32x8*)(x + (size_t)(ptb + lrow)*INC + 8*lgrp);
    }

    for (int tt = wave; tt < T; tt += 4){
        const int ttn = tt + 4;
        float2 s2_n; f32x8 xa_n;
        if (ttn < T){
            const int ptbn = blk_base + ttn * 16;
            s2_n = ((const float2*)sc)[ptbn + lrow];
            xa_n = *(const f32x8*)(x + (size_t)(ptbn + lrow)*INC + 8*lgrp);
        }

        int ix = (int)(s2_c.x * 8.0f); ix = ix < 0 ? 0 : (ix > 7 ? 7 : ix);
        int iy = (int)(s2_c.y * 8.0f); iy = iy < 0 ? 0 : (iy > 7 ? 7 : iy);
        const int lc = (iy << 3) + ix;

        const int lcq0 = __shfl(lc, 4*lgrp + 0, 64);
        const int lcq1 = __shfl(lc, 4*lgrp + 1, 64);
        const int lcq2 = __shfl(lc, 4*lgrp + 2, 64);
        const int lcq3 = __shfl(lc, 4*lgrp + 3, 64);

        bf16x8 Ah, Al;
        split8v(xa_c, Ah, Al);

        f32x4 a0 = (f32x4){0.f,0.f,0.f,0.f}, a1 = a0, a2 = a0, a3 = a0;
        a0 = mfma16(Al, Bh0, a0); a1 = mfma16(Al, Bh1, a1);
        a2 = mfma16(Al, Bh2, a2); a3 = mfma16(Al, Bh3, a3);
        a0 = mfma16(Ah, Bl0, a0); a1 = mfma16(Ah, Bl1, a1);
        a2 = mfma16(Ah, Bl2, a2); a3 = mfma16(Ah, Bl3, a3);
        a0 = mfma16(Ah, Bh0, a0); a1 = mfma16(Ah, Bh1, a1);
        a2 = mfma16(Ah, Bh2, a2); a3 = mfma16(Ah, Bh3, a3);

        if (lane < 16) atomicAdd(&cntl[lc], 1);

        unsafeAtomicAdd(&accL[lcq0*STR +  0 + lrow], gelu_f(a0[0] + bnt0));
        unsafeAtomicAdd(&accL[lcq1*STR +  0 + lrow], gelu_f(a0[1] + bnt0));
        unsafeAtomicAdd(&accL[lcq2*STR +  0 + lrow], gelu_f(a0[2] + bnt0));
        unsafeAtomicAdd(&accL[lcq3*STR +  0 + lrow], gelu_f(a0[3] + bnt0));
        unsafeAtomicAdd(&accL[lcq0*STR + 16 + lrow], gelu_f(a1[0] + bnt1));
        unsafeAtomicAdd(&accL[lcq1*STR + 16 + lrow], gelu_f(a1[1] + bnt1));
        unsafeAtomicAdd(&accL[lcq2*STR + 16 + lrow], gelu_f(a1[2] + bnt1));
        unsafeAtomicAdd(&accL[lcq3*STR + 16 + lrow], gelu_f(a1[3] + bnt1));
        unsafeAtomicAdd(&accL[lcq0*STR + 32 + lrow], gelu_f(a2[0] + bnt2));
        unsafeAtomicAdd(&accL[lcq1*STR + 32 + lrow], gelu_f(a2[1] + bnt2));
        unsafeAtomicAdd(&accL[lcq2*STR + 32 + lrow], gelu_f(a2[2] + bnt2));
        unsafeAtomicAdd(&accL[lcq3*STR + 32 + lrow], gelu_f(a2[3] + bnt2));
        unsafeAtomicAdd(&accL[lcq0*STR + 48 + lrow], gelu_f(a3[0] + bnt3));
        unsafeAtomicAdd(&accL[lcq1*STR + 48 + lrow], gelu_f(a3[1] + bnt3));
        unsafeAtomicAdd(&accL[lcq2*STR + 48 + lrow], gelu_f(a3[2] + bnt3));
        unsafeAtomicAdd(&accL[lcq3*STR + 48 + lrow], gelu_f(a3[3] + bnt3));

        s2_c = s2_n; xa_c = xa_n;
    }
    __syncthreads();

    float* pt = partial + (size_t)blockIdx.x * 4096;
    for (int k = t; k < 4096; k += 256){
        const int r = k >> 6, cc = k & 63;
        pt[k] = accL[r*STR + cc];
    }
    if (t < 64) pcnt[blockIdx.x * 64 + t] = cntl[t];
}

// ---------------- K2: reduce partials (4-way parallel), mean -> Wv2 -> Wt1-tail -> z ----
__global__ __launch_bounds__(256) void k_cluster(
    const float* __restrict__ partial, const int* __restrict__ pcnt,
    const float* __restrict__ Wv2, const float* __restrict__ bv2,
    const float* __restrict__ Wt1, const float* __restrict__ bt1,
    float* __restrict__ z, int bpb)
{
    __shared__ float red[4][HID];
    __shared__ int   redn[4];
    __shared__ float m[HID];
    __shared__ float ph[HID];
    const int c = blockIdx.x;
    const int t = threadIdx.x, j = t & 63, sl = t >> 6;
    const int batch = c >> 6, lc = c & 63;

    float s = 0.0f;
    int   n = 0;
    const size_t pb0 = (size_t)batch * bpb;
    #pragma unroll 4
    for (int b = sl; b < bpb; b += 4){
        s += partial[(pb0 + b) * 4096 + (lc << 6) + j];
        n += pcnt[(pb0 + b) * 64 + lc];
    }
    red[sl][j] = s;
    if (j == 0) redn[sl] = n;
    __syncthreads();

    if (sl == 0){
        float stot = red[0][j] + red[1][j] + red[2][j] + red[3][j];
        int   ntot = redn[0] + redn[1] + redn[2] + redn[3];
        const float inv = (ntot > 0) ? (1.0f / (float)ntot) : 0.0f;
        m[j] = stot * inv;
        __builtin_amdgcn_s_barrier();      // wave-local view; 64 threads only
        float a = bv2[j];
        #pragma unroll 8
        for (int i = 0; i < HID; i++) a += m[i] * Wv2[i*HID + j];
        if (ntot == 0) a = 0.0f;           // reference: pooled = 0 for empty cluster
        ph[j] = a;
        __builtin_amdgcn_s_barrier();
        float b = bt1[j];
        #pragma unroll 8
        for (int i = 0; i < HID; i++) b += ph[i] * Wt1[(2 + i)*HID + j];
        z[c*HID + j] = b;
    }
}

// ---------------- K3: MFMA target MLP, z-slice staged in LDS, per-batch blocks ----------
__global__ __launch_bounds__(256, 3) void k_tgt(
    const float* __restrict__ tc,
    const float* __restrict__ z, const float* __restrict__ Wt1,
    const float* __restrict__ Wt2, const float* __restrict__ bt2,
    float* __restrict__ out, int npb, int TT, int bpt)
{
    __shared__ float zs[64*STRZ];
    const int t = threadIdx.x;
    const int wave = t >> 6, lane = t & 63;
    const int lrow = lane & 15, lgrp = lane >> 4;
    const int batch = blockIdx.x / bpt;
    const int toff  = (blockIdx.x % bpt) * TT;

    // stage this batch's z slice (64 x 64) into padded LDS
    for (int k = t; k < 4096; k += 256)
        zs[(k >> 6)*STRZ + (k & 63)] = z[(size_t)(batch*64)*HID + k];

    // B-fragments of Wt2, Wt1 coord rows, bias
    bf16x8 Bh00, Bh01, Bh10, Bh11, Bl00, Bl01, Bl10, Bl11;
    f32x8 w0v0, w0v1, w1v0, w1v1;
    {
        f32x8 w;
        #pragma unroll
        for (int j = 0; j < 8; j++) w[j] = Wt2[( 0 + 8*lgrp + j)*OUTC +  0 + lrow];
        split8v(w, Bh00, Bl00);
        #pragma unroll
        for (int j = 0; j < 8; j++) w[j] = Wt2[( 0 + 8*lgrp + j)*OUTC + 16 + lrow];
        split8v(w, Bh01, Bl01);
        #pragma unroll
        for (int j = 0; j < 8; j++) w[j] = Wt2[(32 + 8*lgrp + j)*OUTC +  0 + lrow];
        split8v(w, Bh10, Bl10);
        #pragma unroll
        for (int j = 0; j < 8; j++) w[j] = Wt2[(32 + 8*lgrp + j)*OUTC + 16 + lrow];
        split8v(w, Bh11, Bl11);
        #pragma unroll
        for (int j = 0; j < 8; j++){
            w0v0[j] = Wt1[ 0 + 8*lgrp + j];
            w0v1[j] = Wt1[32 + 8*lgrp + j];
            w1v0[j] = Wt1[HID +  0 + 8*lgrp + j];
            w1v1[j] = Wt1[HID + 32 + 8*lgrp + j];
        }
    }
    const float bo0 = bt2[lrow], bo1 = bt2[16 + lrow];
    __syncthreads();

    const size_t pbase = (size_t)batch * npb;

    float2 c2_c = ((const float2*)tc)[pbase + (size_t)(toff + wave)*16 + lrow];

    for (int tt = toff + wave; tt < toff + TT; tt += 4){
        const int ttn = tt + 4;
        float2 c2_n;
        if (ttn < toff + TT)
            c2_n = ((const float2*)tc)[pbase + (size_t)ttn*16 + lrow];

        int ix = (int)(c2_c.x * 8.0f); ix = ix < 0 ? 0 : (ix > 7 ? 7 : ix);
        int iy = (int)(c2_c.y * 8.0f); iy = iy < 0 ? 0 : (iy > 7 ? 7 : iy);
        const int zb = ((iy << 3) + ix) * STRZ;

        f32x8 z0 = *(const f32x8*)(&zs[zb +  0 + 8*lgrp]);
        f32x8 z1 = *(const f32x8*)(&zs[zb + 32 + 8*lgrp]);
        f32x8 g0, g1;
        #pragma unroll
        for (int j = 0; j < 8; j++){
            g0[j] = gelu_f(z0[j] + c2_c.x * w0v0[j] + c2_c.y * w1v0[j]);
            g1[j] = gelu_f(z1[j] + c2_c.x * w0v1[j] + c2_c.y * w1v1[j]);
        }
        bf16x8 Ah0, Al0, Ah1, Al1;
        split8v(g0, Ah0, Al0);
        split8v(g1, Ah1, Al1);

        f32x4 a0 = (f32x4){0.f,0.f,0.f,0.f}, a1 = a0;
        a0 = mfma16(Al0, Bh00, a0); a1 = mfma16(Al0, Bh01, a1);
        a0 = mfma16(Ah0, Bl00, a0); a1 = mfma16(Ah0, Bl01, a1);
        a0 = mfma16(Ah0, Bh00, a0); a1 = mfma16(Ah0, Bh01, a1);
        a0 = mfma16(Al1, Bh10, a0); a1 = mfma16(Al1, Bh11, a1);
        a0 = mfma16(Ah1, Bl10, a0); a1 = mfma16(Ah1, Bl11, a1);
        a0 = mfma16(Ah1, Bh10, a0); a1 = mfma16(Ah1, Bh11, a1);

        const size_t prow = pbase + (size_t)tt*16 + 4*lgrp;
        #pragma unroll
        for (int q = 0; q < 4; q++){
            out[(prow + q)*OUTC +  0 + lrow] = a0[q] + bo0;
            out[(prow + q)*OUTC + 16 + lrow] = a1[q] + bo1;
        }
        c2_c = c2_n;
    }
}

extern "C" void kernel_launch(void* const* d_in, const int* in_sizes, int n_in,
                              void* d_out, int out_size, void* d_ws, size_t ws_size,
                              hipStream_t stream)
{
    const float* x   = (const float*)d_in[0];
    const float* sc  = (const float*)d_in[1];
    const int*   sb  = (const int*)  d_in[2];  (void)sb;
    const float* tc  = (const float*)d_in[3];
    const int*   tb  = (const int*)  d_in[4];  (void)tb;
    const float* Wv1 = (const float*)d_in[5];
    const float* bv1 = (const float*)d_in[6];
    const float* Wv2 = (const float*)d_in[7];
    const float* bv2 = (const float*)d_in[8];
    const float* Wt1 = (const float*)d_in[9];
    const float* bt1 = (const float*)d_in[10];
    const float* Wt2 = (const float*)d_in[11];
    const float* bt2 = (const float*)d_in[12];
    float* out = (float*)d_out;

    const int n   = in_sizes[2];     // total points
    const int npb = n / 8;           // points per batch (src/tgt batch = repeat)
    const int tiles_pb = npb / 16;   // 6250 for 100k

    // bpb = largest divisor of tiles_pb <= 250 whose partials fit in ws
    int bpb = 1;
    for (int d = 250; d >= 1; d--){
        if (tiles_pb % d) continue;
        size_t need = (size_t)(8*d) * (4096 + 64) * 4 + (size_t)NC * HID * 4 + 4096;
        if (need <= ws_size){ bpb = d; break; }
    }
    const int T    = tiles_pb / bpb;
    const int nblk = 8 * bpb;

    char* ws = (char*)d_ws;
    float* partial = (float*)(ws);                                    // nblk*4096*4
    int*   pcnt    = (int*)(ws + (size_t)nblk * 4096 * 4);            // nblk*64*4
    float* z       = (float*)(ws + (size_t)nblk * 4096 * 4 + (size_t)nblk * 64 * 4);

    k_src    <<<nblk, 256, 0, stream>>>(x, sc, Wv1, bv1, partial, pcnt, npb, T, bpb);
    k_cluster<<<NC, 256, 0, stream>>>(partial, pcnt, Wv2, bv2, Wt1, bt1, z, bpb);

    // k_tgt: per-batch blocks; TT = divisor of tiles_pb (~2000 blocks total)
    int TT = 1;
    const int cands[5] = {25, 10, 5, 2, 1};
    for (int ci = 0; ci < 5; ci++){
        if (tiles_pb % cands[ci] == 0){ TT = cands[ci]; break; }
    }
    const int bpt = tiles_pb / TT;
    k_tgt    <<<8*bpt, 256, 0, stream>>>(tc, z, Wt1, Wt2, bt2, out, npb, TT, bpt);
}

// Round 8
// 158.293 us; speedup vs baseline: 10.7080x; 2.0492x over previous
//
#include <hip/hip_runtime.h>

#define NC   512      // BATCH(8) * 8 * 8
#define INC  32
#define HID  64
#define OUTC 32
#define STRZ 68       // padded LDS stride for z slice in k_tgt

typedef __attribute__((ext_vector_type(8))) __bf16 bf16x8;
typedef __attribute__((ext_vector_type(4))) float  f32x4;
typedef __attribute__((ext_vector_type(8))) float  f32x8;
typedef __attribute__((ext_vector_type(8))) unsigned int   u32x8;
typedef __attribute__((ext_vector_type(8))) unsigned short u16x8;
typedef __attribute__((ext_vector_type(4))) unsigned short u16x4;

static __device__ __forceinline__ f32x4 mfma16(bf16x8 a, bf16x8 b, f32x4 c){
    return __builtin_amdgcn_mfma_f32_16x16x32_bf16(a, b, c, 0, 0, 0);
}

// fast exact-GELU: erf via Abramowitz-Stegun 7.1.26 (|err|<=1.5e-7)
__device__ __forceinline__ float gelu_f(float v){
    const float s  = v * 0.70710678118654752f;
    const float as = fabsf(s);
    const float t  = __builtin_amdgcn_rcpf(__builtin_fmaf(0.3275911f, as, 1.0f));
    const float e  = __expf(-as * as);
    float p = __builtin_fmaf(1.061405429f, t, -1.453152027f);
    p = __builtin_fmaf(p, t, 1.421413741f);
    p = __builtin_fmaf(p, t, -0.284496736f);
    p = __builtin_fmaf(p, t, 0.254829592f);
    p = p * t;
    float er = __builtin_fmaf(-p, e, 1.0f);   // erf(|s|)
    er = copysignf(er, s);
    return 0.5f * v * (1.0f + er);
}

// value-typed 3-term split: x ~= hi + lo (each bf16-truncated)
__device__ __forceinline__ void split8v(f32x8 x, bf16x8& hi, bf16x8& lo){
    u32x8 ux = __builtin_bit_cast(u32x8, x);
    f32x8 hf = __builtin_bit_cast(f32x8, ux & 0xFFFF0000u);
    f32x8 lf = x - hf;                               // exact in f32
    u32x8 ul = __builtin_bit_cast(u32x8, lf);
    hi = __builtin_bit_cast(bf16x8, __builtin_convertvector(ux >> 16, u16x8));
    lo = __builtin_bit_cast(bf16x8, __builtin_convertvector(ul >> 16, u16x8));
}

// round-to-nearest-even f32 -> bf16 bits
__device__ __forceinline__ unsigned short rneb(float f){
    unsigned int u = __float_as_uint(f);
    u += 0x7FFFu + ((u >> 16) & 1u);
    return (unsigned short)(u >> 16);
}

// ---------------- K1: MFMA MLP layer-1 + GELU + MFMA one-hot pooling (NO atomics) ----
__global__ __launch_bounds__(256, 2) void k_src(
    const float* __restrict__ x, const float* __restrict__ sc,
    const float* __restrict__ Wv1, const float* __restrict__ bv1,
    float* __restrict__ partial, float* __restrict__ pcntf,
    int npb, int T, int bpb)
{
    __shared__ ushort gbuf[4][64][32];   // [wave][ch][pt]  (wave-private, plain DS ops)
    __shared__ ushort lcw[4][32];        // [wave][pt] cluster ids
    const int t = threadIdx.x;
    const int wave = t >> 6, lane = t & 63;
    const int lrow = lane & 15, lgrp = lane >> 4;
    const int batch = blockIdx.x / bpb;
    const int pb    = blockIdx.x % bpb;

    // main-GEMM B-fragments (Wv1 hi/lo) + bias (layout validated rounds 5-7)
    bf16x8 Bh0, Bh1, Bh2, Bh3, Bl0, Bl1, Bl2, Bl3;
    float bnt0, bnt1, bnt2, bnt3;
    {
        f32x8 w;
        #pragma unroll
        for (int j = 0; j < 8; j++) w[j] = Wv1[(8*lgrp + j)*HID +  0 + lrow];
        split8v(w, Bh0, Bl0);  bnt0 = bv1[ 0 + lrow];
        #pragma unroll
        for (int j = 0; j < 8; j++) w[j] = Wv1[(8*lgrp + j)*HID + 16 + lrow];
        split8v(w, Bh1, Bl1);  bnt1 = bv1[16 + lrow];
        #pragma unroll
        for (int j = 0; j < 8; j++) w[j] = Wv1[(8*lgrp + j)*HID + 32 + lrow];
        split8v(w, Bh2, Bl2);  bnt2 = bv1[32 + lrow];
        #pragma unroll
        for (int j = 0; j < 8; j++) w[j] = Wv1[(8*lgrp + j)*HID + 48 + lrow];
        split8v(w, Bh3, Bl3);  bnt3 = bv1[48 + lrow];
    }
    // ones fragment for exact counting
    u16x8 onesu;
    #pragma unroll
    for (int j = 0; j < 8; j++) onesu[j] = 0x3F80u;
    const bf16x8 ONE = __builtin_bit_cast(bf16x8, onesu);

    // pooled accumulators: P[ct][nt] covers cluster rows 16ct.. x channels 16nt..
    f32x4 P[4][4], C[4];
    #pragma unroll
    for (int ct = 0; ct < 4; ct++){
        C[ct] = (f32x4){0.f,0.f,0.f,0.f};
        #pragma unroll
        for (int nt = 0; nt < 4; nt++) P[ct][nt] = (f32x4){0.f,0.f,0.f,0.f};
    }

    const int base  = batch * npb + pb * T * 16;
    const int PAIRS = T >> 1;            // process 32 points (2 tiles) per iteration

    for (int p = wave; p < PAIRS; p += 4){
        const int pt0 = base + p * 32;
        const float2 sA = ((const float2*)sc)[pt0 + lrow];
        const float2 sB = ((const float2*)sc)[pt0 + 16 + lrow];
        f32x8 xA = *(const f32x8*)(x + (size_t)(pt0 + lrow)*INC + 8*lgrp);
        f32x8 xB = *(const f32x8*)(x + (size_t)(pt0 + 16 + lrow)*INC + 8*lgrp);

        int ixA = (int)(sA.x * 8.0f); ixA = ixA < 0 ? 0 : (ixA > 7 ? 7 : ixA);
        int iyA = (int)(sA.y * 8.0f); iyA = iyA < 0 ? 0 : (iyA > 7 ? 7 : iyA);
        const int lcA = (iyA << 3) + ixA;
        int ixB = (int)(sB.x * 8.0f); ixB = ixB < 0 ? 0 : (ixB > 7 ? 7 : ixB);
        int iyB = (int)(sB.y * 8.0f); iyB = iyB < 0 ? 0 : (iyB > 7 ? 7 : iyB);
        const int lcB = (iyB << 3) + ixB;
        lcw[wave][lrow]      = (ushort)lcA;   // dup writes across lgrp: same value
        lcw[wave][16 + lrow] = (ushort)lcB;

        // ---- half A: h = x@Wv1, gelu, pack bf16 into gbuf[ch][pt] ----
        {
            bf16x8 Ah, Al; split8v(xA, Ah, Al);
            f32x4 a0 = (f32x4){0.f,0.f,0.f,0.f}, a1 = a0, a2 = a0, a3 = a0;
            a0 = mfma16(Al, Bh0, a0); a1 = mfma16(Al, Bh1, a1);
            a2 = mfma16(Al, Bh2, a2); a3 = mfma16(Al, Bh3, a3);
            a0 = mfma16(Ah, Bl0, a0); a1 = mfma16(Ah, Bl1, a1);
            a2 = mfma16(Ah, Bl2, a2); a3 = mfma16(Ah, Bl3, a3);
            a0 = mfma16(Ah, Bh0, a0); a1 = mfma16(Ah, Bh1, a1);
            a2 = mfma16(Ah, Bh2, a2); a3 = mfma16(Ah, Bh3, a3);
            u16x4 w4;
            w4[0]=rneb(gelu_f(a0[0]+bnt0)); w4[1]=rneb(gelu_f(a0[1]+bnt0));
            w4[2]=rneb(gelu_f(a0[2]+bnt0)); w4[3]=rneb(gelu_f(a0[3]+bnt0));
            *(u16x4*)&gbuf[wave][ 0 + lrow][4*lgrp] = w4;
            w4[0]=rneb(gelu_f(a1[0]+bnt1)); w4[1]=rneb(gelu_f(a1[1]+bnt1));
            w4[2]=rneb(gelu_f(a1[2]+bnt1)); w4[3]=rneb(gelu_f(a1[3]+bnt1));
            *(u16x4*)&gbuf[wave][16 + lrow][4*lgrp] = w4;
            w4[0]=rneb(gelu_f(a2[0]+bnt2)); w4[1]=rneb(gelu_f(a2[1]+bnt2));
            w4[2]=rneb(gelu_f(a2[2]+bnt2)); w4[3]=rneb(gelu_f(a2[3]+bnt2));
            *(u16x4*)&gbuf[wave][32 + lrow][4*lgrp] = w4;
            w4[0]=rneb(gelu_f(a3[0]+bnt3)); w4[1]=rneb(gelu_f(a3[1]+bnt3));
            w4[2]=rneb(gelu_f(a3[2]+bnt3)); w4[3]=rneb(gelu_f(a3[3]+bnt3));
            *(u16x4*)&gbuf[wave][48 + lrow][4*lgrp] = w4;
        }
        // ---- half B ----
        {
            bf16x8 Ah, Al; split8v(xB, Ah, Al);
            f32x4 a0 = (f32x4){0.f,0.f,0.f,0.f}, a1 = a0, a2 = a0, a3 = a0;
            a0 = mfma16(Al, Bh0, a0); a1 = mfma16(Al, Bh1, a1);
            a2 = mfma16(Al, Bh2, a2); a3 = mfma16(Al, Bh3, a3);
            a0 = mfma16(Ah, Bl0, a0); a1 = mfma16(Ah, Bl1, a1);
            a2 = mfma16(Ah, Bl2, a2); a3 = mfma16(Ah, Bl3, a3);
            a0 = mfma16(Ah, Bh0, a0); a1 = mfma16(Ah, Bh1, a1);
            a2 = mfma16(Ah, Bh2, a2); a3 = mfma16(Ah, Bh3, a3);
            u16x4 w4;
            w4[0]=rneb(gelu_f(a0[0]+bnt0)); w4[1]=rneb(gelu_f(a0[1]+bnt0));
            w4[2]=rneb(gelu_f(a0[2]+bnt0)); w4[3]=rneb(gelu_f(a0[3]+bnt0));
            *(u16x4*)&gbuf[wave][ 0 + lrow][16 + 4*lgrp] = w4;
            w4[0]=rneb(gelu_f(a1[0]+bnt1)); w4[1]=rneb(gelu_f(a1[1]+bnt1));
            w4[2]=rneb(gelu_f(a1[2]+bnt1)); w4[3]=rneb(gelu_f(a1[3]+bnt1));
            *(u16x4*)&gbuf[wave][16 + lrow][16 + 4*lgrp] = w4;
            w4[0]=rneb(gelu_f(a2[0]+bnt2)); w4[1]=rneb(gelu_f(a2[1]+bnt2));
            w4[2]=rneb(gelu_f(a2[2]+bnt2)); w4[3]=rneb(gelu_f(a2[3]+bnt2));
            *(u16x4*)&gbuf[wave][32 + lrow][16 + 4*lgrp] = w4;
            w4[0]=rneb(gelu_f(a3[0]+bnt3)); w4[1]=rneb(gelu_f(a3[1]+bnt3));
            w4[2]=rneb(gelu_f(a3[2]+bnt3)); w4[3]=rneb(gelu_f(a3[3]+bnt3));
            *(u16x4*)&gbuf[wave][48 + lrow][16 + 4*lgrp] = w4;
        }

        // ---- pooling: P += onehot(lc) @ g  (16 MFMAs), counts via ones-frag ----
        u16x8 lcv = *(const u16x8*)&lcw[wave][8*lgrp];
        bf16x8 g0 = *(const bf16x8*)&gbuf[wave][ 0 + lrow][8*lgrp];
        bf16x8 g1 = *(const bf16x8*)&gbuf[wave][16 + lrow][8*lgrp];
        bf16x8 g2 = *(const bf16x8*)&gbuf[wave][32 + lrow][8*lgrp];
        bf16x8 g3 = *(const bf16x8*)&gbuf[wave][48 + lrow][8*lgrp];
        #pragma unroll
        for (int ct = 0; ct < 4; ct++){
            u16x8 ohu;
            #pragma unroll
            for (int j = 0; j < 8; j++)
                ohu[j] = (lcv[j] == (ushort)(16*ct + lrow)) ? (ushort)0x3F80u : (ushort)0;
            const bf16x8 oh = __builtin_bit_cast(bf16x8, ohu);
            P[ct][0] = mfma16(oh, g0, P[ct][0]);
            P[ct][1] = mfma16(oh, g1, P[ct][1]);
            P[ct][2] = mfma16(oh, g2, P[ct][2]);
            P[ct][3] = mfma16(oh, g3, P[ct][3]);
            C[ct]    = mfma16(oh, ONE, C[ct]);
        }
    }

    // epilogue: one partial slot per wave, plain coalesced stores
    const int slot = blockIdx.x * 4 + wave;
    float* dst = partial + (size_t)slot * 4096;
    #pragma unroll
    for (int ct = 0; ct < 4; ct++)
        #pragma unroll
        for (int nt = 0; nt < 4; nt++)
            #pragma unroll
            for (int reg = 0; reg < 4; reg++)
                dst[(16*ct + 4*lgrp + reg)*64 + 16*nt + lrow] = P[ct][nt][reg];
    if (lrow == 0){
        #pragma unroll
        for (int ct = 0; ct < 4; ct++)
            #pragma unroll
            for (int reg = 0; reg < 4; reg++)
                pcntf[(size_t)slot*64 + 16*ct + 4*lgrp + reg] = C[ct][reg];
    }
}

// ---------------- K2: reduce wave-slots, mean -> Wv2 -> Wt1-tail -> z ----------------
__global__ __launch_bounds__(256) void k_cluster(
    const float* __restrict__ partial, const float* __restrict__ pcntf,
    const float* __restrict__ Wv2, const float* __restrict__ bv2,
    const float* __restrict__ Wt1, const float* __restrict__ bt1,
    float* __restrict__ z, int spb)
{
    __shared__ float red[4][HID];
    __shared__ float redn[4];
    __shared__ float m[HID];
    __shared__ float ph[HID];
    const int c = blockIdx.x;
    const int t = threadIdx.x, j = t & 63, sl = t >> 6;
    const int batch = c >> 6, lc = c & 63;

    float s = 0.0f, cn = 0.0f;
    for (int b = sl; b < spb; b += 4){
        const size_t slot = (size_t)batch * spb + b;
        s  += partial[slot * 4096 + (size_t)lc * 64 + j];
        cn += pcntf[slot * 64 + lc];
    }
    red[sl][j] = s;
    if (j == 0) redn[sl] = cn;
    __syncthreads();

    if (sl == 0){
        float stot = red[0][j] + red[1][j] + red[2][j] + red[3][j];
        float ntot = redn[0] + redn[1] + redn[2] + redn[3];
        const float inv = (ntot > 0.0f) ? (1.0f / ntot) : 0.0f;
        m[j] = stot * inv;
        __builtin_amdgcn_s_barrier();
        float a = bv2[j];
        #pragma unroll 8
        for (int i = 0; i < HID; i++) a += m[i] * Wv2[i*HID + j];
        if (ntot <= 0.0f) a = 0.0f;   // reference: pooled = 0 for empty cluster
        ph[j] = a;
        __builtin_amdgcn_s_barrier();
        float b = bt1[j];
        #pragma unroll 8
        for (int i = 0; i < HID; i++) b += ph[i] * Wt1[(2 + i)*HID + j];
        z[c*HID + j] = b;
    }
}

// ---------------- K3: MFMA target MLP, z-slice staged in LDS, per-batch blocks --------
__global__ __launch_bounds__(256, 3) void k_tgt(
    const float* __restrict__ tc,
    const float* __restrict__ z, const float* __restrict__ Wt1,
    const float* __restrict__ Wt2, const float* __restrict__ bt2,
    float* __restrict__ out, int npb, int TT, int bpt)
{
    __shared__ float zs[64*STRZ];
    const int t = threadIdx.x;
    const int wave = t >> 6, lane = t & 63;
    const int lrow = lane & 15, lgrp = lane >> 4;
    const int batch = blockIdx.x / bpt;
    const int toff  = (blockIdx.x % bpt) * TT;

    for (int k = t; k < 4096; k += 256)
        zs[(k >> 6)*STRZ + (k & 63)] = z[(size_t)(batch*64)*HID + k];

    bf16x8 Bh00, Bh01, Bh10, Bh11, Bl00, Bl01, Bl10, Bl11;
    f32x8 w0v0, w0v1, w1v0, w1v1;
    {
        f32x8 w;
        #pragma unroll
        for (int j = 0; j < 8; j++) w[j] = Wt2[( 0 + 8*lgrp + j)*OUTC +  0 + lrow];
        split8v(w, Bh00, Bl00);
        #pragma unroll
        for (int j = 0; j < 8; j++) w[j] = Wt2[( 0 + 8*lgrp + j)*OUTC + 16 + lrow];
        split8v(w, Bh01, Bl01);
        #pragma unroll
        for (int j = 0; j < 8; j++) w[j] = Wt2[(32 + 8*lgrp + j)*OUTC +  0 + lrow];
        split8v(w, Bh10, Bl10);
        #pragma unroll
        for (int j = 0; j < 8; j++) w[j] = Wt2[(32 + 8*lgrp + j)*OUTC + 16 + lrow];
        split8v(w, Bh11, Bl11);
        #pragma unroll
        for (int j = 0; j < 8; j++){
            w0v0[j] = Wt1[ 0 + 8*lgrp + j];
            w0v1[j] = Wt1[32 + 8*lgrp + j];
            w1v0[j] = Wt1[HID +  0 + 8*lgrp + j];
            w1v1[j] = Wt1[HID + 32 + 8*lgrp + j];
        }
    }
    const float bo0 = bt2[lrow], bo1 = bt2[16 + lrow];
    __syncthreads();

    const size_t pbase = (size_t)batch * npb;
    float2 c2_c = ((const float2*)tc)[pbase + (size_t)(toff + wave)*16 + lrow];

    for (int tt = toff + wave; tt < toff + TT; tt += 4){
        const int ttn = tt + 4;
        float2 c2_n = c2_c;
        if (ttn < toff + TT)
            c2_n = ((const float2*)tc)[pbase + (size_t)ttn*16 + lrow];

        int ix = (int)(c2_c.x * 8.0f); ix = ix < 0 ? 0 : (ix > 7 ? 7 : ix);
        int iy = (int)(c2_c.y * 8.0f); iy = iy < 0 ? 0 : (iy > 7 ? 7 : iy);
        const int zb = ((iy << 3) + ix) * STRZ;

        f32x8 z0 = *(const f32x8*)(&zs[zb +  0 + 8*lgrp]);
        f32x8 z1 = *(const f32x8*)(&zs[zb + 32 + 8*lgrp]);
        f32x8 g0, g1;
        #pragma unroll
        for (int j = 0; j < 8; j++){
            g0[j] = gelu_f(z0[j] + c2_c.x * w0v0[j] + c2_c.y * w1v0[j]);
            g1[j] = gelu_f(z1[j] + c2_c.x * w0v1[j] + c2_c.y * w1v1[j]);
        }
        bf16x8 Ah0, Al0, Ah1, Al1;
        split8v(g0, Ah0, Al0);
        split8v(g1, Ah1, Al1);

        f32x4 a0 = (f32x4){0.f,0.f,0.f,0.f}, a1 = a0;
        a0 = mfma16(Al0, Bh00, a0); a1 = mfma16(Al0, Bh01, a1);
        a0 = mfma16(Ah0, Bl00, a0); a1 = mfma16(Ah0, Bl01, a1);
        a0 = mfma16(Ah0, Bh00, a0); a1 = mfma16(Ah0, Bh01, a1);
        a0 = mfma16(Al1, Bh10, a0); a1 = mfma16(Al1, Bh11, a1);
        a0 = mfma16(Ah1, Bl10, a0); a1 = mfma16(Ah1, Bl11, a1);
        a0 = mfma16(Ah1, Bh10, a0); a1 = mfma16(Ah1, Bh11, a1);

        const size_t prow = pbase + (size_t)tt*16 + 4*lgrp;
        #pragma unroll
        for (int q = 0; q < 4; q++){
            out[(prow + q)*OUTC +  0 + lrow] = a0[q] + bo0;
            out[(prow + q)*OUTC + 16 + lrow] = a1[q] + bo1;
        }
        c2_c = c2_n;
    }
}

extern "C" void kernel_launch(void* const* d_in, const int* in_sizes, int n_in,
                              void* d_out, int out_size, void* d_ws, size_t ws_size,
                              hipStream_t stream)
{
    const float* x   = (const float*)d_in[0];
    const float* sc  = (const float*)d_in[1];
    const int*   sb  = (const int*)  d_in[2];  (void)sb;
    const float* tc  = (const float*)d_in[3];
    const int*   tb  = (const int*)  d_in[4];  (void)tb;
    const float* Wv1 = (const float*)d_in[5];
    const float* bv1 = (const float*)d_in[6];
    const float* Wv2 = (const float*)d_in[7];
    const float* bv2 = (const float*)d_in[8];
    const float* Wt1 = (const float*)d_in[9];
    const float* bt1 = (const float*)d_in[10];
    const float* Wt2 = (const float*)d_in[11];
    const float* bt2 = (const float*)d_in[12];
    float* out = (float*)d_out;

    const int n   = in_sizes[2];     // total points
    const int npb = n / 8;           // points per batch (src/tgt batch = repeat)
    const int tiles_pb = npb / 16;   // 6250

    // pick bpb: divisor of tiles_pb with even T, largest whose slots fit in ws
    int bpb = 1;
    const int cands[4] = {125, 25, 5, 1};
    for (int ci = 0; ci < 4; ci++){
        const int d = cands[ci];
        if (tiles_pb % d) continue;
        if ((tiles_pb / d) & 1) continue;                 // T must be even (pairs)
        const size_t slots = (size_t)8 * d * 4;
        const size_t need  = slots * 4096 * 4 + slots * 64 * 4 + (size_t)NC*HID*4 + 4096;
        if (need <= ws_size){ bpb = d; break; }
    }
    const int T    = tiles_pb / bpb;
    const int nblk = 8 * bpb;
    const int spb  = 4 * bpb;                             // partial slots per batch
    const size_t slots = (size_t)nblk * 4;

    char* ws = (char*)d_ws;
    float* partial = (float*)(ws);                        // slots * 4096 f32
    float* pcntf   = (float*)(ws + slots * 4096 * 4);     // slots * 64 f32
    float* z       = (float*)(ws + slots * 4096 * 4 + slots * 64 * 4);

    k_src    <<<nblk, 256, 0, stream>>>(x, sc, Wv1, bv1, partial, pcntf, npb, T, bpb);
    k_cluster<<<NC, 256, 0, stream>>>(partial, pcntf, Wv2, bv2, Wt1, bt1, z, spb);

    int TT = 1;
    const int tcands[5] = {25, 10, 5, 2, 1};
    for (int ci = 0; ci < 5; ci++){
        if (tiles_pb % tcands[ci] == 0){ TT = tcands[ci]; break; }
    }
    const int bpt = tiles_pb / TT;
    k_tgt    <<<8*bpt, 256, 0, stream>>>(tc, z, Wt1, Wt2, bt2, out, npb, TT, bpt);
}

// Round 9
// 108.155 us; speedup vs baseline: 15.6721x; 1.4636x over previous
//
#include <hip/hip_runtime.h>

#define NC   512      // BATCH(8) * 8 * 8
#define INC  32
#define HID  64
#define OUTC 32
#define STRZ 68       // padded LDS stride for z slice in k_tgt
#define GSTR 36       // gbuf row stride in ushorts (72 B: 8B-aligned, bank stride 18)

typedef __attribute__((ext_vector_type(8))) __bf16 bf16x8;
typedef __attribute__((ext_vector_type(4))) float  f32x4;
typedef __attribute__((ext_vector_type(8))) float  f32x8;
typedef __attribute__((ext_vector_type(8))) unsigned int   u32x8;
typedef __attribute__((ext_vector_type(8))) unsigned short u16x8;
typedef __attribute__((ext_vector_type(4))) unsigned short u16x4;

static __device__ __forceinline__ f32x4 mfma16(bf16x8 a, bf16x8 b, f32x4 c){
    return __builtin_amdgcn_mfma_f32_16x16x32_bf16(a, b, c, 0, 0, 0);
}

// fast exact-GELU: erf via Abramowitz-Stegun 7.1.26 (|err|<=1.5e-7)
__device__ __forceinline__ float gelu_f(float v){
    const float s  = v * 0.70710678118654752f;
    const float as = fabsf(s);
    const float t  = __builtin_amdgcn_rcpf(__builtin_fmaf(0.3275911f, as, 1.0f));
    const float e  = __expf(-as * as);
    float p = __builtin_fmaf(1.061405429f, t, -1.453152027f);
    p = __builtin_fmaf(p, t, 1.421413741f);
    p = __builtin_fmaf(p, t, -0.284496736f);
    p = __builtin_fmaf(p, t, 0.254829592f);
    p = p * t;
    float er = __builtin_fmaf(-p, e, 1.0f);   // erf(|s|)
    er = copysignf(er, s);
    return 0.5f * v * (1.0f + er);
}

// value-typed 3-term split: x ~= hi + lo (each bf16-truncated)
__device__ __forceinline__ void split8v(f32x8 x, bf16x8& hi, bf16x8& lo){
    u32x8 ux = __builtin_bit_cast(u32x8, x);
    f32x8 hf = __builtin_bit_cast(f32x8, ux & 0xFFFF0000u);
    f32x8 lf = x - hf;                               // exact in f32
    u32x8 ul = __builtin_bit_cast(u32x8, lf);
    hi = __builtin_bit_cast(bf16x8, __builtin_convertvector(ux >> 16, u16x8));
    lo = __builtin_bit_cast(bf16x8, __builtin_convertvector(ul >> 16, u16x8));
}

// round-to-nearest-even f32 -> bf16 bits
__device__ __forceinline__ unsigned short rneb(float f){
    unsigned int u = __float_as_uint(f);
    u += 0x7FFFu + ((u >> 16) & 1u);
    return (unsigned short)(u >> 16);
}

// ---------------- K1: MFMA MLP layer-1 + GELU + cross-wave quadrant MFMA pooling ----
// Round: each wave computes gelu(x@Wv1+b1) for its 32-pt pair into shared gbuf
// (double-buffered, padded rows), barrier, then pools ONLY its 16-cluster quadrant
// over all 4 wave buffers. One partial slot per block; no atomics anywhere.
__global__ __launch_bounds__(256, 3) void k_src(
    const float* __restrict__ x, const float* __restrict__ sc,
    const float* __restrict__ Wv1, const float* __restrict__ bv1,
    float* __restrict__ partial, float* __restrict__ pcntf,
    int npb, int T, int bpb)
{
    __shared__ ushort gbuf[2][4][64][GSTR];   // [buf][srcwave][ch][pt(+pad)]
    __shared__ ushort lcw[2][4][32];          // [buf][srcwave][pt] cluster ids
    const int t = threadIdx.x;
    const int wave = t >> 6, lane = t & 63;
    const int lrow = lane & 15, lgrp = lane >> 4;
    const int batch = blockIdx.x / bpb;
    const int pb    = blockIdx.x % bpb;

    // main-GEMM B-fragments (Wv1 hi/lo) + bias (layout validated rounds 5-8)
    bf16x8 Bh0, Bh1, Bh2, Bh3, Bl0, Bl1, Bl2, Bl3;
    float bnt0, bnt1, bnt2, bnt3;
    {
        f32x8 w;
        #pragma unroll
        for (int j = 0; j < 8; j++) w[j] = Wv1[(8*lgrp + j)*HID +  0 + lrow];
        split8v(w, Bh0, Bl0);  bnt0 = bv1[ 0 + lrow];
        #pragma unroll
        for (int j = 0; j < 8; j++) w[j] = Wv1[(8*lgrp + j)*HID + 16 + lrow];
        split8v(w, Bh1, Bl1);  bnt1 = bv1[16 + lrow];
        #pragma unroll
        for (int j = 0; j < 8; j++) w[j] = Wv1[(8*lgrp + j)*HID + 32 + lrow];
        split8v(w, Bh2, Bl2);  bnt2 = bv1[32 + lrow];
        #pragma unroll
        for (int j = 0; j < 8; j++) w[j] = Wv1[(8*lgrp + j)*HID + 48 + lrow];
        split8v(w, Bh3, Bl3);  bnt3 = bv1[48 + lrow];
    }
    u16x8 onesu;
    #pragma unroll
    for (int j = 0; j < 8; j++) onesu[j] = 0x3F80u;
    const bf16x8 ONE = __builtin_bit_cast(bf16x8, onesu);

    // quadrant pooled accumulators (cluster rows 16*wave .. 16*wave+15)
    f32x4 P0 = (f32x4){0.f,0.f,0.f,0.f}, P1 = P0, P2 = P0, P3 = P0, C = P0;

    const int base   = batch * npb + pb * T * 16;
    const int PAIRS  = T >> 1;
    const int rounds = (PAIRS + 3) >> 2;

    // software pipeline: current pair's inputs in registers
    int  p_cur  = wave;
    bool a_cur  = p_cur < PAIRS;
    float2 sA_c, sB_c; f32x8 xA_c, xB_c;
    if (a_cur){
        const int pt0 = base + p_cur * 32;
        sA_c = ((const float2*)sc)[pt0 + lrow];
        sB_c = ((const float2*)sc)[pt0 + 16 + lrow];
        xA_c = *(const f32x8*)(x + (size_t)(pt0 + lrow)*INC + 8*lgrp);
        xB_c = *(const f32x8*)(x + (size_t)(pt0 + 16 + lrow)*INC + 8*lgrp);
    }

    for (int r = 0; r < rounds; r++){
        const int buf = r & 1;
        // prefetch next round
        const int  p_nxt = p_cur + 4;
        const bool a_nxt = p_nxt < PAIRS;
        float2 sA_n, sB_n; f32x8 xA_n, xB_n;
        if (a_nxt){
            const int pt0 = base + p_nxt * 32;
            sA_n = ((const float2*)sc)[pt0 + lrow];
            sB_n = ((const float2*)sc)[pt0 + 16 + lrow];
            xA_n = *(const f32x8*)(x + (size_t)(pt0 + lrow)*INC + 8*lgrp);
            xB_n = *(const f32x8*)(x + (size_t)(pt0 + 16 + lrow)*INC + 8*lgrp);
        }

        if (a_cur){
            int ixA = (int)(sA_c.x * 8.0f); ixA = ixA < 0 ? 0 : (ixA > 7 ? 7 : ixA);
            int iyA = (int)(sA_c.y * 8.0f); iyA = iyA < 0 ? 0 : (iyA > 7 ? 7 : iyA);
            int ixB = (int)(sB_c.x * 8.0f); ixB = ixB < 0 ? 0 : (ixB > 7 ? 7 : ixB);
            int iyB = (int)(sB_c.y * 8.0f); iyB = iyB < 0 ? 0 : (iyB > 7 ? 7 : iyB);
            if (lgrp == 0){
                lcw[buf][wave][lrow]      = (ushort)((iyA << 3) + ixA);
                lcw[buf][wave][16 + lrow] = (ushort)((iyB << 3) + ixB);
            }
            {   // half A: pts 0-15 of the pair
                bf16x8 Ah, Al; split8v(xA_c, Ah, Al);
                f32x4 a0 = (f32x4){0.f,0.f,0.f,0.f}, a1 = a0, a2 = a0, a3 = a0;
                a0 = mfma16(Al, Bh0, a0); a1 = mfma16(Al, Bh1, a1);
                a2 = mfma16(Al, Bh2, a2); a3 = mfma16(Al, Bh3, a3);
                a0 = mfma16(Ah, Bl0, a0); a1 = mfma16(Ah, Bl1, a1);
                a2 = mfma16(Ah, Bl2, a2); a3 = mfma16(Ah, Bl3, a3);
                a0 = mfma16(Ah, Bh0, a0); a1 = mfma16(Ah, Bh1, a1);
                a2 = mfma16(Ah, Bh2, a2); a3 = mfma16(Ah, Bh3, a3);
                u16x4 w4;
                w4[0]=rneb(gelu_f(a0[0]+bnt0)); w4[1]=rneb(gelu_f(a0[1]+bnt0));
                w4[2]=rneb(gelu_f(a0[2]+bnt0)); w4[3]=rneb(gelu_f(a0[3]+bnt0));
                *(u16x4*)&gbuf[buf][wave][ 0 + lrow][4*lgrp] = w4;
                w4[0]=rneb(gelu_f(a1[0]+bnt1)); w4[1]=rneb(gelu_f(a1[1]+bnt1));
                w4[2]=rneb(gelu_f(a1[2]+bnt1)); w4[3]=rneb(gelu_f(a1[3]+bnt1));
                *(u16x4*)&gbuf[buf][wave][16 + lrow][4*lgrp] = w4;
                w4[0]=rneb(gelu_f(a2[0]+bnt2)); w4[1]=rneb(gelu_f(a2[1]+bnt2));
                w4[2]=rneb(gelu_f(a2[2]+bnt2)); w4[3]=rneb(gelu_f(a2[3]+bnt2));
                *(u16x4*)&gbuf[buf][wave][32 + lrow][4*lgrp] = w4;
                w4[0]=rneb(gelu_f(a3[0]+bnt3)); w4[1]=rneb(gelu_f(a3[1]+bnt3));
                w4[2]=rneb(gelu_f(a3[2]+bnt3)); w4[3]=rneb(gelu_f(a3[3]+bnt3));
                *(u16x4*)&gbuf[buf][wave][48 + lrow][4*lgrp] = w4;
            }
            {   // half B: pts 16-31
                bf16x8 Ah, Al; split8v(xB_c, Ah, Al);
                f32x4 a0 = (f32x4){0.f,0.f,0.f,0.f}, a1 = a0, a2 = a0, a3 = a0;
                a0 = mfma16(Al, Bh0, a0); a1 = mfma16(Al, Bh1, a1);
                a2 = mfma16(Al, Bh2, a2); a3 = mfma16(Al, Bh3, a3);
                a0 = mfma16(Ah, Bl0, a0); a1 = mfma16(Ah, Bl1, a1);
                a2 = mfma16(Ah, Bl2, a2); a3 = mfma16(Ah, Bl3, a3);
                a0 = mfma16(Ah, Bh0, a0); a1 = mfma16(Ah, Bh1, a1);
                a2 = mfma16(Ah, Bh2, a2); a3 = mfma16(Ah, Bh3, a3);
                u16x4 w4;
                w4[0]=rneb(gelu_f(a0[0]+bnt0)); w4[1]=rneb(gelu_f(a0[1]+bnt0));
                w4[2]=rneb(gelu_f(a0[2]+bnt0)); w4[3]=rneb(gelu_f(a0[3]+bnt0));
                *(u16x4*)&gbuf[buf][wave][ 0 + lrow][16 + 4*lgrp] = w4;
                w4[0]=rneb(gelu_f(a1[0]+bnt1)); w4[1]=rneb(gelu_f(a1[1]+bnt1));
                w4[2]=rneb(gelu_f(a1[2]+bnt1)); w4[3]=rneb(gelu_f(a1[3]+bnt1));
                *(u16x4*)&gbuf[buf][wave][16 + lrow][16 + 4*lgrp] = w4;
                w4[0]=rneb(gelu_f(a2[0]+bnt2)); w4[1]=rneb(gelu_f(a2[1]+bnt2));
                w4[2]=rneb(gelu_f(a2[2]+bnt2)); w4[3]=rneb(gelu_f(a2[3]+bnt2));
                *(u16x4*)&gbuf[buf][wave][32 + lrow][16 + 4*lgrp] = w4;
                w4[0]=rneb(gelu_f(a3[0]+bnt3)); w4[1]=rneb(gelu_f(a3[1]+bnt3));
                w4[2]=rneb(gelu_f(a3[2]+bnt3)); w4[3]=rneb(gelu_f(a3[3]+bnt3));
                *(u16x4*)&gbuf[buf][wave][48 + lrow][16 + 4*lgrp] = w4;
            }
        } else {
            // inactive tail wave: no-match ids + zero g (0 * garbage would NaN)
            if (lgrp == 0){
                lcw[buf][wave][lrow]      = 0xFFFFu;
                lcw[buf][wave][16 + lrow] = 0xFFFFu;
            }
            u16x4 zz = (u16x4){0,0,0,0};
            #pragma unroll
            for (int nt = 0; nt < 4; nt++){
                *(u16x4*)&gbuf[buf][wave][16*nt + lrow][4*lgrp] = zz;
                *(u16x4*)&gbuf[buf][wave][16*nt + lrow][16 + 4*lgrp] = zz;
            }
        }
        __syncthreads();

        // pool this wave's quadrant over all 4 source buffers
        const ushort tgt = (ushort)(16*wave + lrow);
        #pragma unroll
        for (int s = 0; s < 4; s++){
            const u16x8 lcv = *(const u16x8*)&lcw[buf][s][8*lgrp];
            u16x8 ohu;
            #pragma unroll
            for (int j = 0; j < 8; j++)
                ohu[j] = (lcv[j] == tgt) ? (ushort)0x3F80u : (ushort)0;
            const bf16x8 oh = __builtin_bit_cast(bf16x8, ohu);
            u16x4 glo, ghi;
            glo = *(const u16x4*)&gbuf[buf][s][ 0 + lrow][8*lgrp];
            ghi = *(const u16x4*)&gbuf[buf][s][ 0 + lrow][8*lgrp + 4];
            bf16x8 g0 = __builtin_bit_cast(bf16x8, __builtin_shufflevector(glo, ghi, 0,1,2,3,4,5,6,7));
            glo = *(const u16x4*)&gbuf[buf][s][16 + lrow][8*lgrp];
            ghi = *(const u16x4*)&gbuf[buf][s][16 + lrow][8*lgrp + 4];
            bf16x8 g1 = __builtin_bit_cast(bf16x8, __builtin_shufflevector(glo, ghi, 0,1,2,3,4,5,6,7));
            glo = *(const u16x4*)&gbuf[buf][s][32 + lrow][8*lgrp];
            ghi = *(const u16x4*)&gbuf[buf][s][32 + lrow][8*lgrp + 4];
            bf16x8 g2 = __builtin_bit_cast(bf16x8, __builtin_shufflevector(glo, ghi, 0,1,2,3,4,5,6,7));
            glo = *(const u16x4*)&gbuf[buf][s][48 + lrow][8*lgrp];
            ghi = *(const u16x4*)&gbuf[buf][s][48 + lrow][8*lgrp + 4];
            bf16x8 g3 = __builtin_bit_cast(bf16x8, __builtin_shufflevector(glo, ghi, 0,1,2,3,4,5,6,7));
            P0 = mfma16(oh, g0, P0);
            P1 = mfma16(oh, g1, P1);
            P2 = mfma16(oh, g2, P2);
            P3 = mfma16(oh, g3, P3);
            C  = mfma16(oh, ONE, C);
        }

        p_cur = p_nxt; a_cur = a_nxt;
        sA_c = sA_n; sB_c = sB_n; xA_c = xA_n; xB_c = xB_n;
    }

    // epilogue: ONE partial slot per block; wave owns cluster rows 16*wave..+15
    float* dst = partial + (size_t)blockIdx.x * 4096;
    #pragma unroll
    for (int reg = 0; reg < 4; reg++){
        const int row = 16*wave + 4*lgrp + reg;
        dst[row*64 +  0 + lrow] = P0[reg];
        dst[row*64 + 16 + lrow] = P1[reg];
        dst[row*64 + 32 + lrow] = P2[reg];
        dst[row*64 + 48 + lrow] = P3[reg];
    }
    if (lrow == 0){
        #pragma unroll
        for (int reg = 0; reg < 4; reg++)
            pcntf[(size_t)blockIdx.x*64 + 16*wave + 4*lgrp + reg] = C[reg];
    }
}

// ---------------- K2: reduce block-slots, mean -> Wv2 -> Wt1-tail -> z ----------------
__global__ __launch_bounds__(256) void k_cluster(
    const float* __restrict__ partial, const float* __restrict__ pcntf,
    const float* __restrict__ Wv2, const float* __restrict__ bv2,
    const float* __restrict__ Wt1, const float* __restrict__ bt1,
    float* __restrict__ z, int spb)
{
    __shared__ float red[4][HID];
    __shared__ float redn[4];
    __shared__ float m[HID];
    __shared__ float ph[HID];
    const int c = blockIdx.x;
    const int t = threadIdx.x, j = t & 63, sl = t >> 6;
    const int batch = c >> 6, lc = c & 63;

    float s = 0.0f, cn = 0.0f;
    for (int b = sl; b < spb; b += 4){
        const size_t slot = (size_t)batch * spb + b;
        s  += partial[slot * 4096 + (size_t)lc * 64 + j];
        cn += pcntf[slot * 64 + lc];
    }
    red[sl][j] = s;
    if (j == 0) redn[sl] = cn;
    __syncthreads();

    if (sl == 0){
        float stot = red[0][j] + red[1][j] + red[2][j] + red[3][j];
        float ntot = redn[0] + redn[1] + redn[2] + redn[3];
        const float inv = (ntot > 0.0f) ? (1.0f / ntot) : 0.0f;
        m[j] = stot * inv;
        __builtin_amdgcn_s_barrier();
        float a = bv2[j];
        #pragma unroll 8
        for (int i = 0; i < HID; i++) a += m[i] * Wv2[i*HID + j];
        if (ntot <= 0.0f) a = 0.0f;   // reference: pooled = 0 for empty cluster
        ph[j] = a;
        __builtin_amdgcn_s_barrier();
        float b = bt1[j];
        #pragma unroll 8
        for (int i = 0; i < HID; i++) b += ph[i] * Wt1[(2 + i)*HID + j];
        z[c*HID + j] = b;
    }
}

// ---------------- K3: MFMA target MLP, z-slice staged in LDS, per-batch blocks --------
__global__ __launch_bounds__(256, 3) void k_tgt(
    const float* __restrict__ tc,
    const float* __restrict__ z, const float* __restrict__ Wt1,
    const float* __restrict__ Wt2, const float* __restrict__ bt2,
    float* __restrict__ out, int npb, int TT, int bpt)
{
    __shared__ float zs[64*STRZ];
    const int t = threadIdx.x;
    const int wave = t >> 6, lane = t & 63;
    const int lrow = lane & 15, lgrp = lane >> 4;
    const int batch = blockIdx.x / bpt;
    const int toff  = (blockIdx.x % bpt) * TT;

    for (int k = t; k < 4096; k += 256)
        zs[(k >> 6)*STRZ + (k & 63)] = z[(size_t)(batch*64)*HID + k];

    bf16x8 Bh00, Bh01, Bh10, Bh11, Bl00, Bl01, Bl10, Bl11;
    f32x8 w0v0, w0v1, w1v0, w1v1;
    {
        f32x8 w;
        #pragma unroll
        for (int j = 0; j < 8; j++) w[j] = Wt2[( 0 + 8*lgrp + j)*OUTC +  0 + lrow];
        split8v(w, Bh00, Bl00);
        #pragma unroll
        for (int j = 0; j < 8; j++) w[j] = Wt2[( 0 + 8*lgrp + j)*OUTC + 16 + lrow];
        split8v(w, Bh01, Bl01);
        #pragma unroll
        for (int j = 0; j < 8; j++) w[j] = Wt2[(32 + 8*lgrp + j)*OUTC +  0 + lrow];
        split8v(w, Bh10, Bl10);
        #pragma unroll
        for (int j = 0; j < 8; j++) w[j] = Wt2[(32 + 8*lgrp + j)*OUTC + 16 + lrow];
        split8v(w, Bh11, Bl11);
        #pragma unroll
        for (int j = 0; j < 8; j++){
            w0v0[j] = Wt1[ 0 + 8*lgrp + j];
            w0v1[j] = Wt1[32 + 8*lgrp + j];
            w1v0[j] = Wt1[HID +  0 + 8*lgrp + j];
            w1v1[j] = Wt1[HID + 32 + 8*lgrp + j];
        }
    }
    const float bo0 = bt2[lrow], bo1 = bt2[16 + lrow];
    __syncthreads();

    const size_t pbase = (size_t)batch * npb;
    float2 c2_c = ((const float2*)tc)[pbase + (size_t)(toff + wave)*16 + lrow];

    for (int tt = toff + wave; tt < toff + TT; tt += 4){
        const int ttn = tt + 4;
        float2 c2_n = c2_c;
        if (ttn < toff + TT)
            c2_n = ((const float2*)tc)[pbase + (size_t)ttn*16 + lrow];

        int ix = (int)(c2_c.x * 8.0f); ix = ix < 0 ? 0 : (ix > 7 ? 7 : ix);
        int iy = (int)(c2_c.y * 8.0f); iy = iy < 0 ? 0 : (iy > 7 ? 7 : iy);
        const int zb = ((iy << 3) + ix) * STRZ;

        f32x8 z0 = *(const f32x8*)(&zs[zb +  0 + 8*lgrp]);
        f32x8 z1 = *(const f32x8*)(&zs[zb + 32 + 8*lgrp]);
        f32x8 g0, g1;
        #pragma unroll
        for (int j = 0; j < 8; j++){
            g0[j] = gelu_f(z0[j] + c2_c.x * w0v0[j] + c2_c.y * w1v0[j]);
            g1[j] = gelu_f(z1[j] + c2_c.x * w0v1[j] + c2_c.y * w1v1[j]);
        }
        bf16x8 Ah0, Al0, Ah1, Al1;
        split8v(g0, Ah0, Al0);
        split8v(g1, Ah1, Al1);

        f32x4 a0 = (f32x4){0.f,0.f,0.f,0.f}, a1 = a0;
        a0 = mfma16(Al0, Bh00, a0); a1 = mfma16(Al0, Bh01, a1);
        a0 = mfma16(Ah0, Bl00, a0); a1 = mfma16(Ah0, Bl01, a1);
        a0 = mfma16(Ah0, Bh00, a0); a1 = mfma16(Ah0, Bh01, a1);
        a0 = mfma16(Al1, Bh10, a0); a1 = mfma16(Al1, Bh11, a1);
        a0 = mfma16(Ah1, Bl10, a0); a1 = mfma16(Ah1, Bl11, a1);
        a0 = mfma16(Ah1, Bh10, a0); a1 = mfma16(Ah1, Bh11, a1);

        const size_t prow = pbase + (size_t)tt*16 + 4*lgrp;
        #pragma unroll
        for (int q = 0; q < 4; q++){
            out[(prow + q)*OUTC +  0 + lrow] = a0[q] + bo0;
            out[(prow + q)*OUTC + 16 + lrow] = a1[q] + bo1;
        }
        c2_c = c2_n;
    }
}

extern "C" void kernel_launch(void* const* d_in, const int* in_sizes, int n_in,
                              void* d_out, int out_size, void* d_ws, size_t ws_size,
                              hipStream_t stream)
{
    const float* x   = (const float*)d_in[0];
    const float* sc  = (const float*)d_in[1];
    const int*   sb  = (const int*)  d_in[2];  (void)sb;
    const float* tc  = (const float*)d_in[3];
    const int*   tb  = (const int*)  d_in[4];  (void)tb;
    const float* Wv1 = (const float*)d_in[5];
    const float* bv1 = (const float*)d_in[6];
    const float* Wv2 = (const float*)d_in[7];
    const float* bv2 = (const float*)d_in[8];
    const float* Wt1 = (const float*)d_in[9];
    const float* bt1 = (const float*)d_in[10];
    const float* Wt2 = (const float*)d_in[11];
    const float* bt2 = (const float*)d_in[12];
    float* out = (float*)d_out;

    const int n   = in_sizes[2];     // total points
    const int npb = n / 8;           // points per batch (src/tgt batch = repeat)
    const int tiles_pb = npb / 16;   // 6250

    // bpb: divisor of tiles_pb (odd divisors -> T even), one slot per block
    int bpb = 1;
    const int cands[4] = {125, 25, 5, 1};
    for (int ci = 0; ci < 4; ci++){
        const int d = cands[ci];
        if (tiles_pb % d) continue;
        if ((tiles_pb / d) & 1) continue;                 // T must be even (pairs)
        const size_t slots = (size_t)8 * d;
        const size_t need  = slots * 4096 * 4 + slots * 64 * 4 + (size_t)NC*HID*4 + 4096;
        if (need <= ws_size){ bpb = d; break; }
    }
    const int T    = tiles_pb / bpb;
    const int nblk = 8 * bpb;
    const size_t slots = (size_t)nblk;

    char* ws = (char*)d_ws;
    float* partial = (float*)(ws);                        // slots * 4096 f32
    float* pcntf   = (float*)(ws + slots * 4096 * 4);     // slots * 64 f32
    float* z       = (float*)(ws + slots * 4096 * 4 + slots * 64 * 4);

    k_src    <<<nblk, 256, 0, stream>>>(x, sc, Wv1, bv1, partial, pcntf, npb, T, bpb);
    k_cluster<<<NC, 256, 0, stream>>>(partial, pcntf, Wv2, bv2, Wt1, bt1, z, bpb);

    int TT = 1;
    const int tcands[5] = {25, 10, 5, 2, 1};
    for (int ci = 0; ci < 5; ci++){
        if (tiles_pb % tcands[ci] == 0){ TT = tcands[ci]; break; }
    }
    const int bpt = tiles_pb / TT;
    k_tgt    <<<8*bpt, 256, 0, stream>>>(tc, z, Wt1, Wt2, bt2, out, npb, TT, bpt);
}